// Round 9
// baseline (883.266 us; speedup 1.0000x reference)
//
#include <hip/hip_runtime.h>

#define BB 8
#define TT 160
#define EE 300
#define HH 128
#define D2 256
#define G3 384
#define PSTR 40   // padded LDS row stride (shorts) for P tiles

typedef __attribute__((ext_vector_type(8))) short bf16x8;
typedef __attribute__((ext_vector_type(4))) float floatx4;

__device__ inline float fsigmoid(float x){ return 1.f/(1.f+__expf(-x)); }
__device__ inline float ftanh(float x){ return 2.f*fsigmoid(2.f*x) - 1.f; }

// truncation split: x ~= hi + lo, each bf16; combined rel err <= ~2^-16
__device__ inline void split2(float x, unsigned short& hi, unsigned short& lo){
  unsigned ux = __float_as_uint(x);
  hi = (unsigned short)(ux>>16);
  float r = x - __uint_as_float(ux & 0xFFFF0000u);
  lo = (unsigned short)(__float_as_uint(r)>>16);
}

// sum across the 4 lanes of a quad (p-dimension) via DPP quad_perm — pure VALU.
__device__ inline float quad_sum(float x){
  x += __uint_as_float(__builtin_amdgcn_mov_dpp(__float_as_uint(x), 0xB1, 0xF, 0xF, true)); // quad_perm [1,0,3,2] : xor 1
  x += __uint_as_float(__builtin_amdgcn_mov_dpp(__float_as_uint(x), 0x4E, 0xF, 0xF, true)); // quad_perm [2,3,0,1] : xor 2
  return x;
}

// ---------------- embedding gather ----------------
__global__ __launch_bounds__(256) void k_embed(const int* ta, const int* tb,
    const float* emb, float* ep, float* ec){
  const int idx = blockIdx.x*256 + threadIdx.x;
  const int per = BB*TT*EE;
  if (idx < per){
    const int e = idx % EE, bt = idx / EE;
    ep[idx] = emb[(long)ta[bt]*EE + e];
  } else {
    const int j = idx - per;
    const int e = j % EE, bt = j / EE;
    ec[j] = emb[(long)tb[bt]*EE + e];
  }
}

// ---------------- hi/lo bf16 split of hp & hc ----------------
__global__ __launch_bounds__(256) void k_splitarr(const float* a, const float* b, int n,
    unsigned short* ahi, unsigned short* alo, unsigned short* bhi, unsigned short* blo){
  const int idx = blockIdx.x*256 + threadIdx.x;
  if (idx < n){
    split2(a[idx], ahi[idx], alo[idx]);
    split2(b[idx], bhi[idx], blo[idx]);
  }
}

// ---------------- weight pre-split: W[N x K](f32) -> hi/lo bf16 [N x Kp], zero-padded ----------------
struct SplitJob { const float* W; unsigned short* hi; unsigned short* lo; int n; int K; int Kp; };
struct SplitJobs { SplitJob j[12]; };

__global__ __launch_bounds__(256) void k_splitw(SplitJobs jobs){
  const SplitJob J = jobs.j[blockIdx.z];
  const int idx = blockIdx.x*256 + threadIdx.x;
  if (idx >= J.n) return;
  const int row = idx / J.Kp, k = idx - row*J.Kp;
  const float v = (k < J.K) ? J.W[(long)row*J.K + k] : 0.f;
  split2(v, J.hi[idx], J.lo[idx]);
}

// ---------------- MFMA GEMM with pre-split W: C = A(f32) @ W^T + bias ----------------
struct GemmSJob {
  const float* A; const unsigned short* Whi; const unsigned short* Wlo; const float* bias;
  float* C; int N; int K; int Kp;
};
struct GemmSJobs { GemmSJob j[6]; };

__global__ __launch_bounds__(256) void k_gemmS(GemmSJobs jobs){
  const GemmSJob J = jobs.j[blockIdx.z];
  const int tid = threadIdx.x;
  const int lane = tid & 63, w = tid >> 6;
  const int l15 = lane & 15, q = lane >> 4;
  const int n0 = blockIdx.x * 64;
  if (n0 >= J.N) return;
  const int K = J.K, Kp = J.Kp;
  const long mrow = blockIdx.y*64 + w*16 + l15;
  const float* Arow = J.A + mrow*K;
  floatx4 acc[4];
  #pragma unroll
  for (int t=0;t<4;t++) acc[t] = (floatx4)0.f;
  const int nch = (K+31)>>5;
  for (int kc=0; kc<nch; kc++){
    const int k0 = kc<<5;
    const int kb = k0 + q*8;
    float av[8];
    if (k0+32 <= K){
      const floatx4 a0 = *(const floatx4*)(Arow+kb);
      const floatx4 a1 = *(const floatx4*)(Arow+kb+4);
      av[0]=a0[0];av[1]=a0[1];av[2]=a0[2];av[3]=a0[3];
      av[4]=a1[0];av[5]=a1[1];av[6]=a1[2];av[7]=a1[3];
    } else {
      #pragma unroll
      for (int j=0;j<8;j++){ const int k=kb+j; av[j] = (k<K)? Arow[k] : 0.f; }
    }
    union { bf16x8 v; unsigned short u[8]; } ahi, alo;
    #pragma unroll
    for (int j=0;j<8;j++) split2(av[j], ahi.u[j], alo.u[j]);
    #pragma unroll
    for (int t=0;t<4;t++){
      const int n = n0 + t*16 + l15;
      const long wo = (long)n*Kp + kb;
      union { bf16x8 v; uint4 d; } whi, wlo;
      whi.d = *(const uint4*)(J.Whi + wo);
      wlo.d = *(const uint4*)(J.Wlo + wo);
      acc[t] = __builtin_amdgcn_mfma_f32_16x16x32_bf16(ahi.v, whi.v, acc[t], 0,0,0);
      acc[t] = __builtin_amdgcn_mfma_f32_16x16x32_bf16(ahi.v, wlo.v, acc[t], 0,0,0);
      acc[t] = __builtin_amdgcn_mfma_f32_16x16x32_bf16(alo.v, whi.v, acc[t], 0,0,0);
    }
  }
  const long rbase = blockIdx.y*64 + w*16 + q*4;
  #pragma unroll
  for (int t=0;t<4;t++){
    const int n = n0 + t*16 + l15;
    const float bv = J.bias ? J.bias[n] : 0.f;
    #pragma unroll
    for (int r=0;r<4;r++)
      J.C[(rbase+r)*(long)J.N + n] = acc[t][r] + bv;
  }
}

// ---------------- GRU scan v8: v5 structure + weights in NAMED registers ----------------
struct GruJob { const float* xg; const float* Whh; const float* bhh; float* out; int ocol; int rev; };
struct GruJobs { GruJob j[4]; };

__global__ __launch_bounds__(512,1) void k_gru(GruJobs jobs){
  const GruJob J = jobs.j[blockIdx.y];
  const int bi = blockIdx.x;
  const int tid = threadIdx.x;
  const int j = tid >> 2, p = tid & 3;
  const int rot = p*8;
  const int base = p*32;
  __shared__ float xgt[16][G3];
  __shared__ float hbuf[16][HH];
  __shared__ float hcur[2][HH];
  const float* r0 = J.Whh + (long)j*HH + base;
  const float* z0 = J.Whh + (long)(HH+j)*HH + base;
  const float* n0 = J.Whh + (long)(2*HH+j)*HH + base;
  // 24 named floatx4 = 96 VGPRs of weights; loads use global pointers only.
  #define LDV(gp,i) (*(const floatx4*)((gp) + (((i)*4 + rot) & 31)))
  const floatx4 wr0=LDV(r0,0), wr1=LDV(r0,1), wr2=LDV(r0,2), wr3=LDV(r0,3),
                wr4=LDV(r0,4), wr5=LDV(r0,5), wr6=LDV(r0,6), wr7=LDV(r0,7);
  const floatx4 wz0=LDV(z0,0), wz1=LDV(z0,1), wz2=LDV(z0,2), wz3=LDV(z0,3),
                wz4=LDV(z0,4), wz5=LDV(z0,5), wz6=LDV(z0,6), wz7=LDV(z0,7);
  const floatx4 wn0=LDV(n0,0), wn1=LDV(n0,1), wn2=LDV(n0,2), wn3=LDV(n0,3),
                wn4=LDV(n0,4), wn5=LDV(n0,5), wn6=LDV(n0,6), wn7=LDV(n0,7);
  #undef LDV
  const float bhr = J.bhh[j];
  const float bhz = J.bhh[HH+j];
  const float bhn = J.bhh[2*HH+j];
  if (tid < 256) ((float*)hcur)[tid] = 0.f;
  float hreg = 0.f;
  __syncthreads();

  for (int s0=0; s0<TT; s0+=16){
    #pragma unroll
    for (int r=0;r<3;r++){
      const int i = r*512 + tid;
      const int row = i/96, c4 = i - row*96;
      const int tt = J.rev ? (TT-1-(s0+row)) : (s0+row);
      *(floatx4*)&xgt[row][c4*4] = *(const floatx4*)(J.xg + ((long)bi*TT + tt)*G3 + c4*4);
    }
    __syncthreads();
    for (int si=0; si<16; si++){
      const int s = s0 + si;
      const int buf = s & 1;
      float ar=0.f, az=0.f, an=0.f;
      #define ACC(i) { \
        const floatx4 h4 = *(const floatx4*)&hcur[buf][base + (((i)*4 + rot) & 31)]; \
        ar += wr##i[0]*h4[0] + wr##i[1]*h4[1] + wr##i[2]*h4[2] + wr##i[3]*h4[3]; \
        az += wz##i[0]*h4[0] + wz##i[1]*h4[1] + wz##i[2]*h4[2] + wz##i[3]*h4[3]; \
        an += wn##i[0]*h4[0] + wn##i[1]*h4[1] + wn##i[2]*h4[2] + wn##i[3]*h4[3]; }
      ACC(0) ACC(1) ACC(2) ACC(3) ACC(4) ACC(5) ACC(6) ACC(7)
      #undef ACC
      const float cxr = xgt[si][j];
      const float cxz = xgt[si][HH+j];
      const float cxn = xgt[si][2*HH+j];
      ar = quad_sum(ar);
      az = quad_sum(az);
      an = quad_sum(an);
      const float gr = fsigmoid(cxr + ar + bhr);
      const float gz = fsigmoid(cxz + az + bhz);
      const float gn = ftanh  (cxn + gr*(an + bhn));
      const float h = (1.f-gz)*gn + gz*hreg;
      hreg = h;
      if (p==0){
        hcur[1-buf][j] = h;
        hbuf[si][j] = h;
      }
      __syncthreads();
    }
    {
      const int row = tid >> 5, c4 = tid & 31;
      const int tt = J.rev ? (TT-1-(s0+row)) : (s0+row);
      *(floatx4*)(J.out + ((long)bi*TT + tt)*D2 + J.ocol + c4*4) = *(const floatx4*)&hbuf[row][c4*4];
    }
  }
}

// ---------------- block softmax over 160 values (256 threads) ----------------
__device__ inline float block_softmax160(float s, int tid, float* red){
  float m = s;
  #pragma unroll
  for (int o=32;o>0;o>>=1) m = fmaxf(m, __shfl_xor(m,o));
  if ((tid&63)==0) red[tid>>6] = m;
  __syncthreads();
  m = fmaxf(fmaxf(red[0],red[1]), fmaxf(red[2],red[3]));
  const float p = (tid<TT) ? __expf(s-m) : 0.f;
  float t = p;
  #pragma unroll
  for (int o=32;o>0;o>>=1) t += __shfl_xor(t,o);
  if ((tid&63)==0) red[4+(tid>>6)] = t;
  __syncthreads();
  const float sum = red[4]+red[5]+red[6]+red[7];
  return p / sum;
}

// ---------------- pairwise product attention v3 (dot & self), CTILE=4, 16 waves ----------------
// R7 post-mortem: v2's structure was right (occupancy 21->40%) but the compiler
// targeted 2 blocks/CU (LDS fits) and capped VGPR at 64 -> the 80-reg accumulator
// set spilled to scratch (WRITE_SIZE 1.6KB->86MB, FETCH 12->66MB, dur 122->192).
// v3 = v2 + __launch_bounds__(1024,4): min 4 waves/EU = one 16-wave block resident,
// VGPR cap 128 >= the ~84 the code needs -> no spill, keep doubled occupancy and
// halved staging.
struct PairJob { const unsigned short* Phi; const unsigned short* Plo;
                 const float* Q; const float* W; const float* V; float* a_out; };

__global__ __launch_bounds__(1024,4) void k_pairattn(PairJob j0, PairJob j1){
  const PairJob J = blockIdx.z ? j1 : j0;
  const int b = blockIdx.y, c0 = blockIdx.x*4;
  const int tid = threadIdx.x;
  const int lane = tid & 63, w16 = tid >> 6;   // 0..15
  const int w = w16 & 7;                        // W row-tile
  const int cg = w16 >> 3;                      // c-group: c0+2cg, c0+2cg+1
  const int l15 = lane & 15, q = lane >> 4;
  __shared__ unsigned short Pb[2*2*160*PSTR];
  __shared__ float Qs[4][D2];
  __shared__ float sc_sh[4][TT];
  __shared__ float red[32];
  {
    const int row = tid >> 8, col = tid & 255;  // 4 rows x 256
    Qs[row][col] = J.Q[((long)b*TT + c0 + row)*D2 + col];
  }
  if (tid < 4*TT) ((float*)sc_sh)[tid] = 0.f;
  const long pbase = (long)b*TT*D2;

  // staging: 2560 uint2 per chunk; 1024 threads -> 3 slots with guard
  const unsigned short* srcp[3];
  unsigned short* dstp[3];
  bool act[3];
  #pragma unroll
  for (int r=0;r<3;r++){
    const int idx = tid + r*1024;
    act[r] = (idx < 2560);
    const int ii = act[r] ? idx : 0;
    const int hl = (ii >= 1280) ? 1 : 0;
    const int e4 = ii - hl*1280;
    const int st = e4 >> 3, sd4 = e4 & 7;
    srcp[r] = (hl ? J.Plo : J.Phi) + pbase + (long)st*D2 + sd4*4;
    dstp[r] = &Pb[((0*2 + hl)*160 + st)*PSTR + sd4*4];
  }
  uint2 stg[3];
  #pragma unroll
  for (int r=0;r<3;r++) if (act[r]) stg[r] = *(const uint2*)(srcp[r]);
  const float* Wbase = J.W + (long)(w*16 + l15)*D2;
  floatx4 wv0 = *(const floatx4*)(Wbase + q*8);
  floatx4 wv1 = *(const floatx4*)(Wbase + q*8 + 4);
  #pragma unroll
  for (int r=0;r<3;r++) if (act[r]) *(uint2*)(dstp[r]) = stg[r];
  __syncthreads();

  floatx4 acc0[10], acc1[10];
  #pragma unroll
  for (int nt=0;nt<10;nt++){ acc0[nt] = (floatx4)0.f; acc1[nt] = (floatx4)0.f; }

  for (int kc=0; kc<8; kc++){
    const floatx4 wc0 = wv0, wc1 = wv1;
    if (kc < 7){
      wv0 = *(const floatx4*)(Wbase + (kc+1)*32 + q*8);
      wv1 = *(const floatx4*)(Wbase + (kc+1)*32 + q*8 + 4);
      #pragma unroll
      for (int r=0;r<3;r++) if (act[r]) stg[r] = *(const uint2*)(srcp[r] + (kc+1)*32);
    }
    const int d0 = kc*32 + q*8;
    const floatx4 q00 = *(const floatx4*)&Qs[2*cg+0][d0];
    const floatx4 q01 = *(const floatx4*)&Qs[2*cg+0][d0+4];
    const floatx4 q10 = *(const floatx4*)&Qs[2*cg+1][d0];
    const floatx4 q11 = *(const floatx4*)&Qs[2*cg+1][d0+4];
    union { bf16x8 v; unsigned short u[8]; } ah0, al0, ah1, al1;
    #pragma unroll
    for (int j=0;j<4;j++){
      split2(wc0[j]*q00[j], ah0.u[j],   al0.u[j]);
      split2(wc1[j]*q01[j], ah0.u[4+j], al0.u[4+j]);
      split2(wc0[j]*q10[j], ah1.u[j],   al1.u[j]);
      split2(wc1[j]*q11[j], ah1.u[4+j], al1.u[4+j]);
    }
    const int buf = kc & 1;
    #pragma unroll
    for (int nt=0;nt<10;nt++){
      const int t = nt*16 + l15;
      union { bf16x8 v; } bh, bl;
      bh.v = *(const bf16x8*)&Pb[((buf*2+0)*160 + t)*PSTR + q*8];
      bl.v = *(const bf16x8*)&Pb[((buf*2+1)*160 + t)*PSTR + q*8];
      acc0[nt] = __builtin_amdgcn_mfma_f32_16x16x32_bf16(ah0.v, bh.v, acc0[nt], 0,0,0);
      acc0[nt] = __builtin_amdgcn_mfma_f32_16x16x32_bf16(ah0.v, bl.v, acc0[nt], 0,0,0);
      acc0[nt] = __builtin_amdgcn_mfma_f32_16x16x32_bf16(al0.v, bh.v, acc0[nt], 0,0,0);
      acc1[nt] = __builtin_amdgcn_mfma_f32_16x16x32_bf16(ah1.v, bh.v, acc1[nt], 0,0,0);
      acc1[nt] = __builtin_amdgcn_mfma_f32_16x16x32_bf16(ah1.v, bl.v, acc1[nt], 0,0,0);
      acc1[nt] = __builtin_amdgcn_mfma_f32_16x16x32_bf16(al1.v, bh.v, acc1[nt], 0,0,0);
    }
    if (kc < 7){
      const int nbuf = 1 - buf;
      #pragma unroll
      for (int r=0;r<3;r++) if (act[r]) *(uint2*)(dstp[r] + nbuf*(2*160*PSTR)) = stg[r];
      __syncthreads();
    }
  }

  float vreg[4];
  #pragma unroll
  for (int r=0;r<4;r++) vreg[r] = J.V[w*16 + q*4 + r];
  #pragma unroll
  for (int nt=0;nt<10;nt++){
    float p0 = 0.f, p1 = 0.f;
    #pragma unroll
    for (int r=0;r<4;r++){
      p0 += vreg[r]*ftanh(acc0[nt][r]);
      p1 += vreg[r]*ftanh(acc1[nt][r]);
    }
    p0 += __shfl_xor(p0,16); p0 += __shfl_xor(p0,32);
    p1 += __shfl_xor(p1,16); p1 += __shfl_xor(p1,32);
    if (q==0){
      atomicAdd(&sc_sh[2*cg+0][nt*16 + l15], p0);
      atomicAdd(&sc_sh[2*cg+1][nt*16 + l15], p1);
    }
  }
  __syncthreads();
  // four-row softmax: 256 threads per row (4 waves each)
  {
    const int row = tid >> 8, t_ = tid & 255;
    float s = (t_ < TT) ? sc_sh[row][t_] : -INFINITY;
    float m = s;
    #pragma unroll
    for (int o=32;o>0;o>>=1) m = fmaxf(m, __shfl_xor(m,o));
    if (lane==0) red[w16] = m;
    __syncthreads();
    m = fmaxf(fmaxf(red[row*4+0],red[row*4+1]), fmaxf(red[row*4+2],red[row*4+3]));
    const float p = (t_ < TT) ? __expf(s-m) : 0.f;
    float su = p;
    #pragma unroll
    for (int o=32;o>0;o>>=1) su += __shfl_xor(su,o);
    if (lane==0) red[16+w16] = su;
    __syncthreads();
    const float ssum = red[16+row*4+0]+red[16+row*4+1]+red[16+row*4+2]+red[16+row*4+3];
    if (t_ < TT) J.a_out[((long)b*TT + c0 + row)*TT + t_] = p/ssum;
  }
}

// ---------------- additive attentions (concat / minus), c-tiled LDS version ----------------
struct AddJob { const float* up; const float* uc; const float* V; float sgn; float* a_out; };

__global__ __launch_bounds__(256) void k_addattn(AddJob j0, AddJob j1){
  const AddJob J = blockIdx.z ? j1 : j0;
  const int b = blockIdx.y, c0 = blockIdx.x*16, tid = threadIdx.x;
  const int ci = tid >> 4, tj = tid & 15;
  __shared__ float ucc[16][132];
  __shared__ float up_sh[16][132];
  __shared__ float vv[HH];
  __shared__ float sc[16][TT];
  if (tid < HH) vv[tid] = J.V[tid];
  for (int i = tid; i < 16*HH; i += 256){
    const int cc = i >> 7, k = i & 127;
    ucc[cc][k] = J.sgn * J.uc[((long)b*TT + c0 + cc)*HH + k];
  }
  __syncthreads();
  for (int tch = 0; tch < 10; tch++){
    for (int i = tid; i < 16*HH; i += 256){
      const int tt = i >> 7, k = i & 127;
      up_sh[tt][k] = J.up[((long)b*TT + tch*16 + tt)*HH + k];
    }
    __syncthreads();
    float a0 = 0.f;
    #pragma unroll 4
    for (int k = 0; k < HH; k += 4){
      const floatx4 u4 = *(const floatx4*)&up_sh[tj][k];
      const floatx4 c4 = *(const floatx4*)&ucc[ci][k];
      a0 += vv[k]*ftanh(u4[0]+c4[0]) + vv[k+1]*ftanh(u4[1]+c4[1])
          + vv[k+2]*ftanh(u4[2]+c4[2]) + vv[k+3]*ftanh(u4[3]+c4[3]);
    }
    sc[ci][tch*16 + tj] = a0;
    __syncthreads();
  }
  float m = -INFINITY;
  float sv[10];
  #pragma unroll
  for (int u = 0; u < 10; u++){ sv[u] = sc[ci][tj + 16*u]; m = fmaxf(m, sv[u]); }
  #pragma unroll
  for (int o = 8; o >= 1; o >>= 1) m = fmaxf(m, __shfl_xor(m, o));
  float ssum = 0.f;
  #pragma unroll
  for (int u = 0; u < 10; u++){ sv[u] = __expf(sv[u] - m); ssum += sv[u]; }
  #pragma unroll
  for (int o = 8; o >= 1; o >>= 1) ssum += __shfl_xor(ssum, o);
  const float inv = 1.f / ssum;
  float* ao = J.a_out + ((long)b*TT + c0 + ci)*TT + tj;
  #pragma unroll
  for (int u = 0; u < 10; u++) ao[16*u] = sv[u]*inv;
}

// ---------------- bilinear attention ----------------
__global__ __launch_bounds__(256) void k_bilattn(const float* hc, const float* hpWb, float* a_out){
  const int b = blockIdx.y, c = blockIdx.x, tid = threadIdx.x;
  __shared__ float hcc[D2];
  __shared__ float red[8];
  if (tid < D2) hcc[tid] = hc[((long)b*TT + c)*D2 + tid];
  __syncthreads();
  float s = -INFINITY;
  if (tid < TT){
    const float* pr = hpWb + ((long)b*TT + tid)*D2;
    float a0 = 0.f;
    #pragma unroll 4
    for (int k=0;k<D2;k++) a0 += hcc[k]*pr[k];
    s = a0;
  }
  const float a = block_softmax160(s, tid, red);
  if (tid < TT) a_out[((long)b*TT + c)*TT + tid] = a;
}

// ---------------- rep build ----------------
__global__ __launch_bounds__(256) void k_rep(const float* hp, const float* hc,
    const float* acat, const float* abil, const float* adot, const float* amin, const float* aself,
    float* aggin){
  const int b = blockIdx.y, c = blockIdx.x, tid = threadIdx.x;
  __shared__ float a5[5][TT];
  {
    const long base = ((long)b*TT + c)*TT;
    for (int i=tid;i<5*TT;i+=256){
      const int which = i/TT, t = i - which*TT;
      const float* p = which==0? acat : which==1? abil : which==2? adot : which==3? amin : aself;
      a5[which][t] = p[base + t];
    }
  }
  __syncthreads();
  const float* hpb = hp + (long)b*TT*D2 + tid;
  const float* hcb = hc + (long)b*TT*D2 + tid;
  float r0=0.f,r1=0.f,r2=0.f,r3=0.f,r4=0.f;
  for (int t=0;t<TT;t++){
    const float vp = hpb[(long)t*D2];
    const float vc = hcb[(long)t*D2];
    r0 += a5[0][t]*vp;
    r1 += a5[1][t]*vp;
    r2 += a5[2][t]*vp;
    r3 += a5[3][t]*vp;
    r4 += a5[4][t]*vc;
  }
  float* o = aggin + ((long)b*TT + c)*(6*D2);
  o[tid]        = hc[((long)b*TT + c)*D2 + tid];
  o[D2 + tid]   = r4;
  o[2*D2 + tid] = r0;
  o[3*D2 + tid] = r2;
  o[4*D2 + tid] = r1;
  o[5*D2 + tid] = r3;
}

// ---------------- tail1 ----------------
__global__ __launch_bounds__(256) void k_tail1(const float* upP, const float* Vp,
    const float* hp, float* rp){
  const int b = blockIdx.x, tid = threadIdx.x;
  __shared__ float vv[HH];
  __shared__ float ap_sh[TT];
  __shared__ float red[8];
  if (tid<HH) vv[tid] = Vp[tid];
  __syncthreads();
  float s = -INFINITY;
  if (tid<TT){
    const float* ur = upP + ((long)b*TT + tid)*HH;
    float a0=0.f;
    #pragma unroll 4
    for (int k=0;k<HH;k++) a0 += vv[k]*ftanh(ur[k]);
    s = a0;
  }
  const float a = block_softmax160(s, tid, red);
  if (tid<TT) ap_sh[tid] = a;
  __syncthreads();
  float acc = 0.f;
  const float* hpb = hp + (long)b*TT*D2 + tid;
  for (int t=0;t<TT;t++) acc += ap_sh[t]*hpb[(long)t*D2];
  rp[b*D2 + tid] = acc;
}

// ---------------- tail2 ----------------
__global__ __launch_bounds__(256) void k_tail2(const float* aggW1, const float* agg, const float* rp,
    const float* W2, const float* Vv, const float* Wout, const float* bout,
    float* out){
  const int b = blockIdx.x, tid = threadIdx.x;
  __shared__ float rps[D2];
  __shared__ float rpw[HH];
  __shared__ float ac_sh[TT];
  __shared__ float rc_sh[D2];
  __shared__ float red[8];
  if (tid < D2) rps[tid] = rp[b*D2 + tid];
  __syncthreads();
  if (tid < HH){
    float a0=0.f;
    const float* wr2 = W2 + (long)tid*D2;
    for (int d=0; d<D2; d+=4){
      const floatx4 w4 = *(const floatx4*)(wr2 + d);
      a0 += w4[0]*rps[d] + w4[1]*rps[d+1] + w4[2]*rps[d+2] + w4[3]*rps[d+3];
    }
    rpw[tid] = a0;
  }
  __syncthreads();
  float s = -INFINITY;
  if (tid < TT){
    const float* ar = aggW1 + ((long)b*TT + tid)*HH;
    float a0=0.f;
    for (int k=0;k<HH;k++) a0 += Vv[k]*(ar[k] + rpw[k]);
    s = a0;
  }
  const float a = block_softmax160(s, tid, red);
  if (tid < TT) ac_sh[tid] = a;
  __syncthreads();
  float rc=0.f;
  const float* ab = agg + (long)b*TT*D2 + tid;
  for (int t=0;t<TT;t++) rc += ac_sh[t]*ab[(long)t*D2];
  rc_sh[tid] = rc;
  __syncthreads();
  if (tid < 2){
    float o = bout[tid];
    const float* wr = Wout + (long)tid*D2;
    for (int d=0; d<D2; d++) o += wr[d]*rc_sh[d];
    out[b*2 + tid] = o;
  }
}

extern "C" void kernel_launch(void* const* d_in, const int* in_sizes, int n_in,
                              void* d_out, int out_size, void* d_ws, size_t ws_size,
                              hipStream_t stream){
  (void)in_sizes; (void)n_in; (void)out_size; (void)ws_size;
  const int* ta = (const int*)d_in[0];
  const int* tb = (const int*)d_in[1];
  const float* emb = (const float*)d_in[2];
  #define F32(i) ((const float*)d_in[i])

  float* ws = (float*)d_ws;
  float* ep    = ws;                 // 8*160*300
  float* ec    = ep    + 384000;
  float* xg_pf = ec    + 384000;     // 8*160*384 each; reused by agg stage later
  float* xg_pb = xg_pf + 491520;
  float* xg_cf = xg_pb + 491520;
  float* xg_cb = xg_cf + 491520;
  float* hp    = xg_cb + 491520;     // 8*160*256
  float* hc    = hp    + 327680;
  float* up1   = hc    + 327680;     // 8*160*128 each
  float* uc2   = up1   + 163840;
  float* ump   = uc2   + 163840;
  float* umc   = ump   + 163840;
  float* upP   = umc   + 163840;
  float* hpWb  = upP   + 163840;     // 8*160*256
  float* acat  = hpWb  + 327680;     // 8*160*160 each
  float* abil  = acat  + 204800;
  float* adot  = abil  + 204800;
  float* amin  = adot  + 204800;
  float* aself = amin  + 204800;
  float* aggin = aself + 204800;     // 8*160*1536
  float* rp    = aggin + 1966080;    // 8*256
  unsigned short* hp_hi = (unsigned short*)(rp + 2048);   // 327680 u16 each
  unsigned short* hp_lo = hp_hi + 327680;
  unsigned short* hc_hi = hp_lo + 327680;
  unsigned short* hc_lo = hc_hi + 327680;
  // pre-split weight region (ushort), padded rows
  unsigned short* wsp = hc_lo + 327680;
  unsigned short* w3h  = wsp;             unsigned short* w3l  = w3h  + 122880;  // 384x320
  unsigned short* w7h  = w3l  + 122880;   unsigned short* w7l  = w7h  + 122880;
  unsigned short* w11h = w7l  + 122880;   unsigned short* w11l = w11h + 122880;
  unsigned short* w15h = w11l + 122880;   unsigned short* w15l = w15h + 122880;
  unsigned short* w27h = w15l + 122880;   unsigned short* w27l = w27h + 32768;   // 128x256
  unsigned short* w28h = w27l + 32768;    unsigned short* w28l = w28h + 32768;
  unsigned short* w33h = w28l + 32768;    unsigned short* w33l = w33h + 32768;
  unsigned short* w37h = w33l + 32768;    unsigned short* w37l = w37h + 32768;
  unsigned short* w30h = w37l + 32768;    unsigned short* w30l = w30h + 65536;   // 256x256
  unsigned short* w19h = w30l + 65536;    unsigned short* w19l = w19h + 589824;  // 384x1536
  unsigned short* w23h = w19l + 589824;   unsigned short* w23l = w23h + 589824;
  unsigned short* w39h = w23l + 589824;   unsigned short* w39l = w39h + 32768;   // 128x256
  // dead-buffer reuse for the agg stage:
  float* xg_af = xg_pf;
  float* xg_ab = xg_pb;
  float* agg   = xg_cf;
  float* aggW1 = xg_cb;

  // 1) embedding gather + weight pre-split
  k_embed<<<dim3(3000), dim3(256), 0, stream>>>(ta, tb, emb, ep, ec);
  SplitJobs sj = {};
  sj.j[0]  = {F32(3),  w3h,  w3l,  122880, 300, 320};
  sj.j[1]  = {F32(7),  w7h,  w7l,  122880, 300, 320};
  sj.j[2]  = {F32(11), w11h, w11l, 122880, 300, 320};
  sj.j[3]  = {F32(15), w15h, w15l, 122880, 300, 320};
  sj.j[4]  = {F32(27), w27h, w27l, 32768,  256, 256};
  sj.j[5]  = {F32(28), w28h, w28l, 32768,  256, 256};
  sj.j[6]  = {F32(33), w33h, w33l, 32768,  256, 256};
  sj.j[7]  = {F32(37), w37h, w37l, 32768,  256, 256};
  sj.j[8]  = {F32(30), w30h, w30l, 65536,  256, 256};
  sj.j[9]  = {F32(19), w19h, w19l, 589824, 1536, 1536};
  sj.j[10] = {F32(23), w23h, w23l, 589824, 1536, 1536};
  sj.j[11] = {F32(39), w39h, w39l, 32768,  256, 256};
  k_splitw<<<dim3(2304,1,12), dim3(256), 0, stream>>>(sj);

  // 2) xg = x @ Wih^T + bih for p/c  (M=1280, N=384, K=300, Kp=320)
  GemmSJobs ja = {};
  ja.j[0] = {ep, w3h,  w3l,  F32(5),  xg_pf, 384, 300, 320};
  ja.j[1] = {ep, w7h,  w7l,  F32(9),  xg_pb, 384, 300, 320};
  ja.j[2] = {ec, w11h, w11l, F32(13), xg_cf, 384, 300, 320};
  ja.j[3] = {ec, w15h, w15l, F32(17), xg_cb, 384, 300, 320};
  k_gemmS<<<dim3(6,20,4), dim3(256), 0, stream>>>(ja);

  // 3) p/c GRU scans (v8)
  GruJobs gj = {};
  gj.j[0] = {xg_pf, F32(4),  F32(6),  hp, 0,   0};
  gj.j[1] = {xg_pb, F32(8),  F32(10), hp, 128, 1};
  gj.j[2] = {xg_cf, F32(12), F32(14), hc, 0,   0};
  gj.j[3] = {xg_cb, F32(16), F32(18), hc, 128, 1};
  k_gru<<<dim3(8,4), dim3(512), 0, stream>>>(gj);

  // 3b) hi/lo split of hp & hc for pairattn B-operands
  k_splitarr<<<dim3(1280), dim3(256), 0, stream>>>(hp, hc, 327680, hp_hi, hp_lo, hc_hi, hc_lo);

  // 4) projection GEMMs (K=256)
  GemmSJobs jb = {};
  jb.j[0] = {hp, w27h, w27l, nullptr, up1,  128, 256, 256};
  jb.j[1] = {hc, w28h, w28l, nullptr, uc2,  128, 256, 256};
  jb.j[2] = {hp, w33h, w33l, nullptr, ump,  128, 256, 256};
  jb.j[3] = {hc, w33h, w33l, nullptr, umc,  128, 256, 256};
  jb.j[4] = {hp, w37h, w37l, nullptr, upP,  128, 256, 256};
  jb.j[5] = {hp, w30h, w30l, nullptr, hpWb, 256, 256, 256};
  k_gemmS<<<dim3(4,20,6), dim3(256), 0, stream>>>(jb);

  // 5) dot & self attentions (v3: CTILE=4, 16 waves, VGPR cap 128)
  PairJob pd  = {hp_hi, hp_lo, hc, F32(31), F32(32), adot};
  PairJob psf = {hc_hi, hc_lo, hc, F32(35), F32(36), aself};
  k_pairattn<<<dim3(40,8,2), dim3(1024), 0, stream>>>(pd, psf);

  // 6) concat & minus attentions (c-tiled)
  AddJob ac_ = {up1, uc2, F32(29),  1.f, acat};
  AddJob am_ = {ump, umc, F32(34), -1.f, amin};
  k_addattn<<<dim3(10,8,2), dim3(256), 0, stream>>>(ac_, am_);

  // 7) bilinear attention
  k_bilattn<<<dim3(160,8), dim3(256), 0, stream>>>(hc, hpWb, abil);

  // 8) ap/rp pooling
  k_tail1<<<dim3(8), dim3(256), 0, stream>>>(upP, F32(38), hp, rp);

  // 9) weighted reps -> agg_in
  k_rep<<<dim3(160,8), dim3(256), 0, stream>>>(hp, hc, acat, abil, adot, amin, aself, aggin);

  // 10) agg xg GEMMs (M=1280, N=384, K=1536)
  GemmSJobs jc = {};
  jc.j[0] = {aggin, w19h, w19l, F32(21), xg_af, 384, 1536, 1536};
  jc.j[1] = {aggin, w23h, w23l, F32(25), xg_ab, 384, 1536, 1536};
  k_gemmS<<<dim3(6,20,2), dim3(256), 0, stream>>>(jc);

  // 11) agg GRU scans (v8)
  GruJobs gja = {};
  gja.j[0] = {xg_af, F32(20), F32(22), agg, 0,   0};
  gja.j[1] = {xg_ab, F32(24), F32(26), agg, 128, 1};
  k_gru<<<dim3(8,2), dim3(512), 0, stream>>>(gja);

  // 12) agg @ W1^T (N=128, K=256)
  GemmSJobs jd = {};
  jd.j[0] = {agg, w39h, w39l, nullptr, aggW1, 128, 256, 256};
  k_gemmS<<<dim3(2,20,1), dim3(256), 0, stream>>>(jd);

  // 13) final scores + output
  k_tail2<<<dim3(8), dim3(256), 0, stream>>>(aggW1, agg, rp, F32(40), F32(41), F32(42), F32(43),
                                             (float*)d_out);
  #undef F32
}

// Round 10
// 880.752 us; speedup vs baseline: 1.0029x; 1.0029x over previous
//
#include <hip/hip_runtime.h>

#define BB 8
#define TT 160
#define EE 300
#define HH 128
#define D2 256
#define G3 384
#define PSTR 40   // padded LDS row stride (shorts) for P tiles

typedef __attribute__((ext_vector_type(8))) short bf16x8;
typedef __attribute__((ext_vector_type(4))) float floatx4;

__device__ inline float fsigmoid(float x){ return 1.f/(1.f+__expf(-x)); }
__device__ inline float ftanh(float x){ return 2.f*fsigmoid(2.f*x) - 1.f; }

// truncation split: x ~= hi + lo, each bf16; combined rel err <= ~2^-16
__device__ inline void split2(float x, unsigned short& hi, unsigned short& lo){
  unsigned ux = __float_as_uint(x);
  hi = (unsigned short)(ux>>16);
  float r = x - __uint_as_float(ux & 0xFFFF0000u);
  lo = (unsigned short)(__float_as_uint(r)>>16);
}

// sum across the 4 lanes of a quad (p-dimension) via DPP quad_perm — pure VALU.
__device__ inline float quad_sum(float x){
  x += __uint_as_float(__builtin_amdgcn_mov_dpp(__float_as_uint(x), 0xB1, 0xF, 0xF, true)); // quad_perm [1,0,3,2] : xor 1
  x += __uint_as_float(__builtin_amdgcn_mov_dpp(__float_as_uint(x), 0x4E, 0xF, 0xF, true)); // quad_perm [2,3,0,1] : xor 2
  return x;
}

// ---------------- embedding gather ----------------
__global__ __launch_bounds__(256) void k_embed(const int* ta, const int* tb,
    const float* emb, float* ep, float* ec){
  const int idx = blockIdx.x*256 + threadIdx.x;
  const int per = BB*TT*EE;
  if (idx < per){
    const int e = idx % EE, bt = idx / EE;
    ep[idx] = emb[(long)ta[bt]*EE + e];
  } else {
    const int j = idx - per;
    const int e = j % EE, bt = j / EE;
    ec[j] = emb[(long)tb[bt]*EE + e];
  }
}

// ---------------- hi/lo bf16 split of hp & hc ----------------
__global__ __launch_bounds__(256) void k_splitarr(const float* a, const float* b, int n,
    unsigned short* ahi, unsigned short* alo, unsigned short* bhi, unsigned short* blo){
  const int idx = blockIdx.x*256 + threadIdx.x;
  if (idx < n){
    split2(a[idx], ahi[idx], alo[idx]);
    split2(b[idx], bhi[idx], blo[idx]);
  }
}

// ---------------- weight pre-split: W[N x K](f32) -> hi/lo bf16 [N x Kp], zero-padded ----------------
struct SplitJob { const float* W; unsigned short* hi; unsigned short* lo; int n; int K; int Kp; };
struct SplitJobs { SplitJob j[12]; };

__global__ __launch_bounds__(256) void k_splitw(SplitJobs jobs){
  const SplitJob J = jobs.j[blockIdx.z];
  const int idx = blockIdx.x*256 + threadIdx.x;
  if (idx >= J.n) return;
  const int row = idx / J.Kp, k = idx - row*J.Kp;
  const float v = (k < J.K) ? J.W[(long)row*J.K + k] : 0.f;
  split2(v, J.hi[idx], J.lo[idx]);
}

// ---------------- MFMA GEMM with pre-split W: C = A(f32) @ W^T + bias ----------------
struct GemmSJob {
  const float* A; const unsigned short* Whi; const unsigned short* Wlo; const float* bias;
  float* C; int N; int K; int Kp;
};
struct GemmSJobs { GemmSJob j[6]; };

__global__ __launch_bounds__(256) void k_gemmS(GemmSJobs jobs){
  const GemmSJob J = jobs.j[blockIdx.z];
  const int tid = threadIdx.x;
  const int lane = tid & 63, w = tid >> 6;
  const int l15 = lane & 15, q = lane >> 4;
  const int n0 = blockIdx.x * 64;
  if (n0 >= J.N) return;
  const int K = J.K, Kp = J.Kp;
  const long mrow = blockIdx.y*64 + w*16 + l15;
  const float* Arow = J.A + mrow*K;
  floatx4 acc[4];
  #pragma unroll
  for (int t=0;t<4;t++) acc[t] = (floatx4)0.f;
  const int nch = (K+31)>>5;
  for (int kc=0; kc<nch; kc++){
    const int k0 = kc<<5;
    const int kb = k0 + q*8;
    float av[8];
    if (k0+32 <= K){
      const floatx4 a0 = *(const floatx4*)(Arow+kb);
      const floatx4 a1 = *(const floatx4*)(Arow+kb+4);
      av[0]=a0[0];av[1]=a0[1];av[2]=a0[2];av[3]=a0[3];
      av[4]=a1[0];av[5]=a1[1];av[6]=a1[2];av[7]=a1[3];
    } else {
      #pragma unroll
      for (int j=0;j<8;j++){ const int k=kb+j; av[j] = (k<K)? Arow[k] : 0.f; }
    }
    union { bf16x8 v; unsigned short u[8]; } ahi, alo;
    #pragma unroll
    for (int j=0;j<8;j++) split2(av[j], ahi.u[j], alo.u[j]);
    #pragma unroll
    for (int t=0;t<4;t++){
      const int n = n0 + t*16 + l15;
      const long wo = (long)n*Kp + kb;
      union { bf16x8 v; uint4 d; } whi, wlo;
      whi.d = *(const uint4*)(J.Whi + wo);
      wlo.d = *(const uint4*)(J.Wlo + wo);
      acc[t] = __builtin_amdgcn_mfma_f32_16x16x32_bf16(ahi.v, whi.v, acc[t], 0,0,0);
      acc[t] = __builtin_amdgcn_mfma_f32_16x16x32_bf16(ahi.v, wlo.v, acc[t], 0,0,0);
      acc[t] = __builtin_amdgcn_mfma_f32_16x16x32_bf16(alo.v, whi.v, acc[t], 0,0,0);
    }
  }
  const long rbase = blockIdx.y*64 + w*16 + q*4;
  #pragma unroll
  for (int t=0;t<4;t++){
    const int n = n0 + t*16 + l15;
    const float bv = J.bias ? J.bias[n] : 0.f;
    #pragma unroll
    for (int r=0;r<4;r++)
      J.C[(rbase+r)*(long)J.N + n] = acc[t][r] + bv;
  }
}

// ---------------- GRU scan v9: v8 + amdgpu_waves_per_eu(2,2) ----------------
// Session-wide spill diagnosis: the LLVM occupancy heuristic sets the VGPR budget
// from LDS-permitted max occupancy (8 waves/EU here -> budget 64) and SPILLS the
// 96-VGPR weight set; __launch_bounds__' 2nd arg only sets the MIN waves/EU and
// cannot lower that target (v5-v8 all hit this). amdgpu_waves_per_eu(2,2) pins the
// budget at 256 (matches real residency: 1 block/CU = 2 waves/SIMD) so the 24
// named floatx4 weights finally stay in registers.
struct GruJob { const float* xg; const float* Whh; const float* bhh; float* out; int ocol; int rev; };
struct GruJobs { GruJob j[4]; };

__global__ __launch_bounds__(512) __attribute__((amdgpu_waves_per_eu(2,2)))
void k_gru(GruJobs jobs){
  const GruJob J = jobs.j[blockIdx.y];
  const int bi = blockIdx.x;
  const int tid = threadIdx.x;
  const int j = tid >> 2, p = tid & 3;
  const int rot = p*8;
  const int base = p*32;
  __shared__ float xgt[16][G3];
  __shared__ float hbuf[16][HH];
  __shared__ float hcur[2][HH];
  const float* r0 = J.Whh + (long)j*HH + base;
  const float* z0 = J.Whh + (long)(HH+j)*HH + base;
  const float* n0 = J.Whh + (long)(2*HH+j)*HH + base;
  // 24 named floatx4 = 96 VGPRs of weights; loads use global pointers only.
  #define LDV(gp,i) (*(const floatx4*)((gp) + (((i)*4 + rot) & 31)))
  const floatx4 wr0=LDV(r0,0), wr1=LDV(r0,1), wr2=LDV(r0,2), wr3=LDV(r0,3),
                wr4=LDV(r0,4), wr5=LDV(r0,5), wr6=LDV(r0,6), wr7=LDV(r0,7);
  const floatx4 wz0=LDV(z0,0), wz1=LDV(z0,1), wz2=LDV(z0,2), wz3=LDV(z0,3),
                wz4=LDV(z0,4), wz5=LDV(z0,5), wz6=LDV(z0,6), wz7=LDV(z0,7);
  const floatx4 wn0=LDV(n0,0), wn1=LDV(n0,1), wn2=LDV(n0,2), wn3=LDV(n0,3),
                wn4=LDV(n0,4), wn5=LDV(n0,5), wn6=LDV(n0,6), wn7=LDV(n0,7);
  #undef LDV
  const float bhr = J.bhh[j];
  const float bhz = J.bhh[HH+j];
  const float bhn = J.bhh[2*HH+j];
  if (tid < 256) ((float*)hcur)[tid] = 0.f;
  float hreg = 0.f;
  __syncthreads();

  for (int s0=0; s0<TT; s0+=16){
    #pragma unroll
    for (int r=0;r<3;r++){
      const int i = r*512 + tid;
      const int row = i/96, c4 = i - row*96;
      const int tt = J.rev ? (TT-1-(s0+row)) : (s0+row);
      *(floatx4*)&xgt[row][c4*4] = *(const floatx4*)(J.xg + ((long)bi*TT + tt)*G3 + c4*4);
    }
    __syncthreads();
    for (int si=0; si<16; si++){
      const int s = s0 + si;
      const int buf = s & 1;
      float ar=0.f, az=0.f, an=0.f;
      #define ACC(i) { \
        const floatx4 h4 = *(const floatx4*)&hcur[buf][base + (((i)*4 + rot) & 31)]; \
        ar += wr##i[0]*h4[0] + wr##i[1]*h4[1] + wr##i[2]*h4[2] + wr##i[3]*h4[3]; \
        az += wz##i[0]*h4[0] + wz##i[1]*h4[1] + wz##i[2]*h4[2] + wz##i[3]*h4[3]; \
        an += wn##i[0]*h4[0] + wn##i[1]*h4[1] + wn##i[2]*h4[2] + wn##i[3]*h4[3]; }
      ACC(0) ACC(1) ACC(2) ACC(3) ACC(4) ACC(5) ACC(6) ACC(7)
      #undef ACC
      const float cxr = xgt[si][j];
      const float cxz = xgt[si][HH+j];
      const float cxn = xgt[si][2*HH+j];
      ar = quad_sum(ar);
      az = quad_sum(az);
      an = quad_sum(an);
      const float gr = fsigmoid(cxr + ar + bhr);
      const float gz = fsigmoid(cxz + az + bhz);
      const float gn = ftanh  (cxn + gr*(an + bhn));
      const float h = (1.f-gz)*gn + gz*hreg;
      hreg = h;
      if (p==0){
        hcur[1-buf][j] = h;
        hbuf[si][j] = h;
      }
      __syncthreads();
    }
    {
      const int row = tid >> 5, c4 = tid & 31;
      const int tt = J.rev ? (TT-1-(s0+row)) : (s0+row);
      *(floatx4*)(J.out + ((long)bi*TT + tt)*D2 + J.ocol + c4*4) = *(const floatx4*)&hbuf[row][c4*4];
    }
  }
}

// ---------------- block softmax over 160 values (256 threads) ----------------
__device__ inline float block_softmax160(float s, int tid, float* red){
  float m = s;
  #pragma unroll
  for (int o=32;o>0;o>>=1) m = fmaxf(m, __shfl_xor(m,o));
  if ((tid&63)==0) red[tid>>6] = m;
  __syncthreads();
  m = fmaxf(fmaxf(red[0],red[1]), fmaxf(red[2],red[3]));
  const float p = (tid<TT) ? __expf(s-m) : 0.f;
  float t = p;
  #pragma unroll
  for (int o=32;o>0;o>>=1) t += __shfl_xor(t,o);
  if ((tid&63)==0) red[4+(tid>>6)] = t;
  __syncthreads();
  const float sum = red[4]+red[5]+red[6]+red[7];
  return p / sum;
}

// ---------------- pairwise product attention v4 (dot & self), CTILE=4, 16 waves ----------------
// R9 post-mortem: __launch_bounds__(1024,4) did NOT stop the spill (VGPR stayed 64,
// WRITE_SIZE stayed 85MB) because the 2nd arg only sets MIN waves/EU; the allocator
// still targeted the LDS-permitted max (2 wgs = 8 waves/EU -> budget 64).
// v4 pins amdgpu_waves_per_eu(4,4): budget exactly 128 >= the ~84-100 needed ->
// no spill, one 16-wave block/CU, CTILE=4 staging savings retained.
struct PairJob { const unsigned short* Phi; const unsigned short* Plo;
                 const float* Q; const float* W; const float* V; float* a_out; };

__global__ __launch_bounds__(1024) __attribute__((amdgpu_waves_per_eu(4,4)))
void k_pairattn(PairJob j0, PairJob j1){
  const PairJob J = blockIdx.z ? j1 : j0;
  const int b = blockIdx.y, c0 = blockIdx.x*4;
  const int tid = threadIdx.x;
  const int lane = tid & 63, w16 = tid >> 6;   // 0..15
  const int w = w16 & 7;                        // W row-tile
  const int cg = w16 >> 3;                      // c-group: c0+2cg, c0+2cg+1
  const int l15 = lane & 15, q = lane >> 4;
  __shared__ unsigned short Pb[2*2*160*PSTR];
  __shared__ float Qs[4][D2];
  __shared__ float sc_sh[4][TT];
  __shared__ float red[32];
  {
    const int row = tid >> 8, col = tid & 255;  // 4 rows x 256
    Qs[row][col] = J.Q[((long)b*TT + c0 + row)*D2 + col];
  }
  if (tid < 4*TT) ((float*)sc_sh)[tid] = 0.f;
  const long pbase = (long)b*TT*D2;

  // staging: 2560 uint2 per chunk; 1024 threads -> 3 slots with guard
  const unsigned short* srcp[3];
  unsigned short* dstp[3];
  bool act[3];
  #pragma unroll
  for (int r=0;r<3;r++){
    const int idx = tid + r*1024;
    act[r] = (idx < 2560);
    const int ii = act[r] ? idx : 0;
    const int hl = (ii >= 1280) ? 1 : 0;
    const int e4 = ii - hl*1280;
    const int st = e4 >> 3, sd4 = e4 & 7;
    srcp[r] = (hl ? J.Plo : J.Phi) + pbase + (long)st*D2 + sd4*4;
    dstp[r] = &Pb[((0*2 + hl)*160 + st)*PSTR + sd4*4];
  }
  uint2 stg[3];
  #pragma unroll
  for (int r=0;r<3;r++) if (act[r]) stg[r] = *(const uint2*)(srcp[r]);
  const float* Wbase = J.W + (long)(w*16 + l15)*D2;
  floatx4 wv0 = *(const floatx4*)(Wbase + q*8);
  floatx4 wv1 = *(const floatx4*)(Wbase + q*8 + 4);
  #pragma unroll
  for (int r=0;r<3;r++) if (act[r]) *(uint2*)(dstp[r]) = stg[r];
  __syncthreads();

  floatx4 acc0[10], acc1[10];
  #pragma unroll
  for (int nt=0;nt<10;nt++){ acc0[nt] = (floatx4)0.f; acc1[nt] = (floatx4)0.f; }

  for (int kc=0; kc<8; kc++){
    const floatx4 wc0 = wv0, wc1 = wv1;
    if (kc < 7){
      wv0 = *(const floatx4*)(Wbase + (kc+1)*32 + q*8);
      wv1 = *(const floatx4*)(Wbase + (kc+1)*32 + q*8 + 4);
      #pragma unroll
      for (int r=0;r<3;r++) if (act[r]) stg[r] = *(const uint2*)(srcp[r] + (kc+1)*32);
    }
    const int d0 = kc*32 + q*8;
    const floatx4 q00 = *(const floatx4*)&Qs[2*cg+0][d0];
    const floatx4 q01 = *(const floatx4*)&Qs[2*cg+0][d0+4];
    const floatx4 q10 = *(const floatx4*)&Qs[2*cg+1][d0];
    const floatx4 q11 = *(const floatx4*)&Qs[2*cg+1][d0+4];
    union { bf16x8 v; unsigned short u[8]; } ah0, al0, ah1, al1;
    #pragma unroll
    for (int j=0;j<4;j++){
      split2(wc0[j]*q00[j], ah0.u[j],   al0.u[j]);
      split2(wc1[j]*q01[j], ah0.u[4+j], al0.u[4+j]);
      split2(wc0[j]*q10[j], ah1.u[j],   al1.u[j]);
      split2(wc1[j]*q11[j], ah1.u[4+j], al1.u[4+j]);
    }
    const int buf = kc & 1;
    #pragma unroll
    for (int nt=0;nt<10;nt++){
      const int t = nt*16 + l15;
      union { bf16x8 v; } bh, bl;
      bh.v = *(const bf16x8*)&Pb[((buf*2+0)*160 + t)*PSTR + q*8];
      bl.v = *(const bf16x8*)&Pb[((buf*2+1)*160 + t)*PSTR + q*8];
      acc0[nt] = __builtin_amdgcn_mfma_f32_16x16x32_bf16(ah0.v, bh.v, acc0[nt], 0,0,0);
      acc0[nt] = __builtin_amdgcn_mfma_f32_16x16x32_bf16(ah0.v, bl.v, acc0[nt], 0,0,0);
      acc0[nt] = __builtin_amdgcn_mfma_f32_16x16x32_bf16(al0.v, bh.v, acc0[nt], 0,0,0);
      acc1[nt] = __builtin_amdgcn_mfma_f32_16x16x32_bf16(ah1.v, bh.v, acc1[nt], 0,0,0);
      acc1[nt] = __builtin_amdgcn_mfma_f32_16x16x32_bf16(ah1.v, bl.v, acc1[nt], 0,0,0);
      acc1[nt] = __builtin_amdgcn_mfma_f32_16x16x32_bf16(al1.v, bh.v, acc1[nt], 0,0,0);
    }
    if (kc < 7){
      const int nbuf = 1 - buf;
      #pragma unroll
      for (int r=0;r<3;r++) if (act[r]) *(uint2*)(dstp[r] + nbuf*(2*160*PSTR)) = stg[r];
      __syncthreads();
    }
  }

  float vreg[4];
  #pragma unroll
  for (int r=0;r<4;r++) vreg[r] = J.V[w*16 + q*4 + r];
  #pragma unroll
  for (int nt=0;nt<10;nt++){
    float p0 = 0.f, p1 = 0.f;
    #pragma unroll
    for (int r=0;r<4;r++){
      p0 += vreg[r]*ftanh(acc0[nt][r]);
      p1 += vreg[r]*ftanh(acc1[nt][r]);
    }
    p0 += __shfl_xor(p0,16); p0 += __shfl_xor(p0,32);
    p1 += __shfl_xor(p1,16); p1 += __shfl_xor(p1,32);
    if (q==0){
      atomicAdd(&sc_sh[2*cg+0][nt*16 + l15], p0);
      atomicAdd(&sc_sh[2*cg+1][nt*16 + l15], p1);
    }
  }
  __syncthreads();
  // four-row softmax: 256 threads per row (4 waves each)
  {
    const int row = tid >> 8, t_ = tid & 255;
    float s = (t_ < TT) ? sc_sh[row][t_] : -INFINITY;
    float m = s;
    #pragma unroll
    for (int o=32;o>0;o>>=1) m = fmaxf(m, __shfl_xor(m,o));
    if (lane==0) red[w16] = m;
    __syncthreads();
    m = fmaxf(fmaxf(red[row*4+0],red[row*4+1]), fmaxf(red[row*4+2],red[row*4+3]));
    const float p = (t_ < TT) ? __expf(s-m) : 0.f;
    float su = p;
    #pragma unroll
    for (int o=32;o>0;o>>=1) su += __shfl_xor(su,o);
    if (lane==0) red[16+w16] = su;
    __syncthreads();
    const float ssum = red[16+row*4+0]+red[16+row*4+1]+red[16+row*4+2]+red[16+row*4+3];
    if (t_ < TT) J.a_out[((long)b*TT + c0 + row)*TT + t_] = p/ssum;
  }
}

// ---------------- additive attentions (concat / minus), c-tiled LDS version ----------------
struct AddJob { const float* up; const float* uc; const float* V; float sgn; float* a_out; };

__global__ __launch_bounds__(256) void k_addattn(AddJob j0, AddJob j1){
  const AddJob J = blockIdx.z ? j1 : j0;
  const int b = blockIdx.y, c0 = blockIdx.x*16, tid = threadIdx.x;
  const int ci = tid >> 4, tj = tid & 15;
  __shared__ float ucc[16][132];
  __shared__ float up_sh[16][132];
  __shared__ float vv[HH];
  __shared__ float sc[16][TT];
  if (tid < HH) vv[tid] = J.V[tid];
  for (int i = tid; i < 16*HH; i += 256){
    const int cc = i >> 7, k = i & 127;
    ucc[cc][k] = J.sgn * J.uc[((long)b*TT + c0 + cc)*HH + k];
  }
  __syncthreads();
  for (int tch = 0; tch < 10; tch++){
    for (int i = tid; i < 16*HH; i += 256){
      const int tt = i >> 7, k = i & 127;
      up_sh[tt][k] = J.up[((long)b*TT + tch*16 + tt)*HH + k];
    }
    __syncthreads();
    float a0 = 0.f;
    #pragma unroll 4
    for (int k = 0; k < HH; k += 4){
      const floatx4 u4 = *(const floatx4*)&up_sh[tj][k];
      const floatx4 c4 = *(const floatx4*)&ucc[ci][k];
      a0 += vv[k]*ftanh(u4[0]+c4[0]) + vv[k+1]*ftanh(u4[1]+c4[1])
          + vv[k+2]*ftanh(u4[2]+c4[2]) + vv[k+3]*ftanh(u4[3]+c4[3]);
    }
    sc[ci][tch*16 + tj] = a0;
    __syncthreads();
  }
  float m = -INFINITY;
  float sv[10];
  #pragma unroll
  for (int u = 0; u < 10; u++){ sv[u] = sc[ci][tj + 16*u]; m = fmaxf(m, sv[u]); }
  #pragma unroll
  for (int o = 8; o >= 1; o >>= 1) m = fmaxf(m, __shfl_xor(m, o));
  float ssum = 0.f;
  #pragma unroll
  for (int u = 0; u < 10; u++){ sv[u] = __expf(sv[u] - m); ssum += sv[u]; }
  #pragma unroll
  for (int o = 8; o >= 1; o >>= 1) ssum += __shfl_xor(ssum, o);
  const float inv = 1.f / ssum;
  float* ao = J.a_out + ((long)b*TT + c0 + ci)*TT + tj;
  #pragma unroll
  for (int u = 0; u < 10; u++) ao[16*u] = sv[u]*inv;
}

// ---------------- bilinear attention ----------------
__global__ __launch_bounds__(256) void k_bilattn(const float* hc, const float* hpWb, float* a_out){
  const int b = blockIdx.y, c = blockIdx.x, tid = threadIdx.x;
  __shared__ float hcc[D2];
  __shared__ float red[8];
  if (tid < D2) hcc[tid] = hc[((long)b*TT + c)*D2 + tid];
  __syncthreads();
  float s = -INFINITY;
  if (tid < TT){
    const float* pr = hpWb + ((long)b*TT + tid)*D2;
    float a0 = 0.f;
    #pragma unroll 4
    for (int k=0;k<D2;k++) a0 += hcc[k]*pr[k];
    s = a0;
  }
  const float a = block_softmax160(s, tid, red);
  if (tid < TT) a_out[((long)b*TT + c)*TT + tid] = a;
}

// ---------------- rep build ----------------
__global__ __launch_bounds__(256) void k_rep(const float* hp, const float* hc,
    const float* acat, const float* abil, const float* adot, const float* amin, const float* aself,
    float* aggin){
  const int b = blockIdx.y, c = blockIdx.x, tid = threadIdx.x;
  __shared__ float a5[5][TT];
  {
    const long base = ((long)b*TT + c)*TT;
    for (int i=tid;i<5*TT;i+=256){
      const int which = i/TT, t = i - which*TT;
      const float* p = which==0? acat : which==1? abil : which==2? adot : which==3? amin : aself;
      a5[which][t] = p[base + t];
    }
  }
  __syncthreads();
  const float* hpb = hp + (long)b*TT*D2 + tid;
  const float* hcb = hc + (long)b*TT*D2 + tid;
  float r0=0.f,r1=0.f,r2=0.f,r3=0.f,r4=0.f;
  for (int t=0;t<TT;t++){
    const float vp = hpb[(long)t*D2];
    const float vc = hcb[(long)t*D2];
    r0 += a5[0][t]*vp;
    r1 += a5[1][t]*vp;
    r2 += a5[2][t]*vp;
    r3 += a5[3][t]*vp;
    r4 += a5[4][t]*vc;
  }
  float* o = aggin + ((long)b*TT + c)*(6*D2);
  o[tid]        = hc[((long)b*TT + c)*D2 + tid];
  o[D2 + tid]   = r4;
  o[2*D2 + tid] = r0;
  o[3*D2 + tid] = r2;
  o[4*D2 + tid] = r1;
  o[5*D2 + tid] = r3;
}

// ---------------- tail1 ----------------
__global__ __launch_bounds__(256) void k_tail1(const float* upP, const float* Vp,
    const float* hp, float* rp){
  const int b = blockIdx.x, tid = threadIdx.x;
  __shared__ float vv[HH];
  __shared__ float ap_sh[TT];
  __shared__ float red[8];
  if (tid<HH) vv[tid] = Vp[tid];
  __syncthreads();
  float s = -INFINITY;
  if (tid<TT){
    const float* ur = upP + ((long)b*TT + tid)*HH;
    float a0=0.f;
    #pragma unroll 4
    for (int k=0;k<HH;k++) a0 += vv[k]*ftanh(ur[k]);
    s = a0;
  }
  const float a = block_softmax160(s, tid, red);
  if (tid<TT) ap_sh[tid] = a;
  __syncthreads();
  float acc = 0.f;
  const float* hpb = hp + (long)b*TT*D2 + tid;
  for (int t=0;t<TT;t++) acc += ap_sh[t]*hpb[(long)t*D2];
  rp[b*D2 + tid] = acc;
}

// ---------------- tail2 ----------------
__global__ __launch_bounds__(256) void k_tail2(const float* aggW1, const float* agg, const float* rp,
    const float* W2, const float* Vv, const float* Wout, const float* bout,
    float* out){
  const int b = blockIdx.x, tid = threadIdx.x;
  __shared__ float rps[D2];
  __shared__ float rpw[HH];
  __shared__ float ac_sh[TT];
  __shared__ float rc_sh[D2];
  __shared__ float red[8];
  if (tid < D2) rps[tid] = rp[b*D2 + tid];
  __syncthreads();
  if (tid < HH){
    float a0=0.f;
    const float* wr2 = W2 + (long)tid*D2;
    for (int d=0; d<D2; d+=4){
      const floatx4 w4 = *(const floatx4*)(wr2 + d);
      a0 += w4[0]*rps[d] + w4[1]*rps[d+1] + w4[2]*rps[d+2] + w4[3]*rps[d+3];
    }
    rpw[tid] = a0;
  }
  __syncthreads();
  float s = -INFINITY;
  if (tid < TT){
    const float* ar = aggW1 + ((long)b*TT + tid)*HH;
    float a0=0.f;
    for (int k=0;k<HH;k++) a0 += Vv[k]*(ar[k] + rpw[k]);
    s = a0;
  }
  const float a = block_softmax160(s, tid, red);
  if (tid < TT) ac_sh[tid] = a;
  __syncthreads();
  float rc=0.f;
  const float* ab = agg + (long)b*TT*D2 + tid;
  for (int t=0;t<TT;t++) rc += ac_sh[t]*ab[(long)t*D2];
  rc_sh[tid] = rc;
  __syncthreads();
  if (tid < 2){
    float o = bout[tid];
    const float* wr = Wout + (long)tid*D2;
    for (int d=0; d<D2; d++) o += wr[d]*rc_sh[d];
    out[b*2 + tid] = o;
  }
}

extern "C" void kernel_launch(void* const* d_in, const int* in_sizes, int n_in,
                              void* d_out, int out_size, void* d_ws, size_t ws_size,
                              hipStream_t stream){
  (void)in_sizes; (void)n_in; (void)out_size; (void)ws_size;
  const int* ta = (const int*)d_in[0];
  const int* tb = (const int*)d_in[1];
  const float* emb = (const float*)d_in[2];
  #define F32(i) ((const float*)d_in[i])

  float* ws = (float*)d_ws;
  float* ep    = ws;                 // 8*160*300
  float* ec    = ep    + 384000;
  float* xg_pf = ec    + 384000;     // 8*160*384 each; reused by agg stage later
  float* xg_pb = xg_pf + 491520;
  float* xg_cf = xg_pb + 491520;
  float* xg_cb = xg_cf + 491520;
  float* hp    = xg_cb + 491520;     // 8*160*256
  float* hc    = hp    + 327680;
  float* up1   = hc    + 327680;     // 8*160*128 each
  float* uc2   = up1   + 163840;
  float* ump   = uc2   + 163840;
  float* umc   = ump   + 163840;
  float* upP   = umc   + 163840;
  float* hpWb  = upP   + 163840;     // 8*160*256
  float* acat  = hpWb  + 327680;     // 8*160*160 each
  float* abil  = acat  + 204800;
  float* adot  = abil  + 204800;
  float* amin  = adot  + 204800;
  float* aself = amin  + 204800;
  float* aggin = aself + 204800;     // 8*160*1536
  float* rp    = aggin + 1966080;    // 8*256
  unsigned short* hp_hi = (unsigned short*)(rp + 2048);   // 327680 u16 each
  unsigned short* hp_lo = hp_hi + 327680;
  unsigned short* hc_hi = hp_lo + 327680;
  unsigned short* hc_lo = hc_hi + 327680;
  // pre-split weight region (ushort), padded rows
  unsigned short* wsp = hc_lo + 327680;
  unsigned short* w3h  = wsp;             unsigned short* w3l  = w3h  + 122880;  // 384x320
  unsigned short* w7h  = w3l  + 122880;   unsigned short* w7l  = w7h  + 122880;
  unsigned short* w11h = w7l  + 122880;   unsigned short* w11l = w11h + 122880;
  unsigned short* w15h = w11l + 122880;   unsigned short* w15l = w15h + 122880;
  unsigned short* w27h = w15l + 122880;   unsigned short* w27l = w27h + 32768;   // 128x256
  unsigned short* w28h = w27l + 32768;    unsigned short* w28l = w28h + 32768;
  unsigned short* w33h = w28l + 32768;    unsigned short* w33l = w33h + 32768;
  unsigned short* w37h = w33l + 32768;    unsigned short* w37l = w37h + 32768;
  unsigned short* w30h = w37l + 32768;    unsigned short* w30l = w30h + 65536;   // 256x256
  unsigned short* w19h = w30l + 65536;    unsigned short* w19l = w19h + 589824;  // 384x1536
  unsigned short* w23h = w19l + 589824;   unsigned short* w23l = w23h + 589824;
  unsigned short* w39h = w23l + 589824;   unsigned short* w39l = w39h + 32768;   // 128x256
  // dead-buffer reuse for the agg stage:
  float* xg_af = xg_pf;
  float* xg_ab = xg_pb;
  float* agg   = xg_cf;
  float* aggW1 = xg_cb;

  // 1) embedding gather + weight pre-split
  k_embed<<<dim3(3000), dim3(256), 0, stream>>>(ta, tb, emb, ep, ec);
  SplitJobs sj = {};
  sj.j[0]  = {F32(3),  w3h,  w3l,  122880, 300, 320};
  sj.j[1]  = {F32(7),  w7h,  w7l,  122880, 300, 320};
  sj.j[2]  = {F32(11), w11h, w11l, 122880, 300, 320};
  sj.j[3]  = {F32(15), w15h, w15l, 122880, 300, 320};
  sj.j[4]  = {F32(27), w27h, w27l, 32768,  256, 256};
  sj.j[5]  = {F32(28), w28h, w28l, 32768,  256, 256};
  sj.j[6]  = {F32(33), w33h, w33l, 32768,  256, 256};
  sj.j[7]  = {F32(37), w37h, w37l, 32768,  256, 256};
  sj.j[8]  = {F32(30), w30h, w30l, 65536,  256, 256};
  sj.j[9]  = {F32(19), w19h, w19l, 589824, 1536, 1536};
  sj.j[10] = {F32(23), w23h, w23l, 589824, 1536, 1536};
  sj.j[11] = {F32(39), w39h, w39l, 32768,  256, 256};
  k_splitw<<<dim3(2304,1,12), dim3(256), 0, stream>>>(sj);

  // 2) xg = x @ Wih^T + bih for p/c  (M=1280, N=384, K=300, Kp=320)
  GemmSJobs ja = {};
  ja.j[0] = {ep, w3h,  w3l,  F32(5),  xg_pf, 384, 300, 320};
  ja.j[1] = {ep, w7h,  w7l,  F32(9),  xg_pb, 384, 300, 320};
  ja.j[2] = {ec, w11h, w11l, F32(13), xg_cf, 384, 300, 320};
  ja.j[3] = {ec, w15h, w15l, F32(17), xg_cb, 384, 300, 320};
  k_gemmS<<<dim3(6,20,4), dim3(256), 0, stream>>>(ja);

  // 3) p/c GRU scans (v9: pinned waves_per_eu)
  GruJobs gj = {};
  gj.j[0] = {xg_pf, F32(4),  F32(6),  hp, 0,   0};
  gj.j[1] = {xg_pb, F32(8),  F32(10), hp, 128, 1};
  gj.j[2] = {xg_cf, F32(12), F32(14), hc, 0,   0};
  gj.j[3] = {xg_cb, F32(16), F32(18), hc, 128, 1};
  k_gru<<<dim3(8,4), dim3(512), 0, stream>>>(gj);

  // 3b) hi/lo split of hp & hc for pairattn B-operands
  k_splitarr<<<dim3(1280), dim3(256), 0, stream>>>(hp, hc, 327680, hp_hi, hp_lo, hc_hi, hc_lo);

  // 4) projection GEMMs (K=256)
  GemmSJobs jb = {};
  jb.j[0] = {hp, w27h, w27l, nullptr, up1,  128, 256, 256};
  jb.j[1] = {hc, w28h, w28l, nullptr, uc2,  128, 256, 256};
  jb.j[2] = {hp, w33h, w33l, nullptr, ump,  128, 256, 256};
  jb.j[3] = {hc, w33h, w33l, nullptr, umc,  128, 256, 256};
  jb.j[4] = {hp, w37h, w37l, nullptr, upP,  128, 256, 256};
  jb.j[5] = {hp, w30h, w30l, nullptr, hpWb, 256, 256, 256};
  k_gemmS<<<dim3(4,20,6), dim3(256), 0, stream>>>(jb);

  // 5) dot & self attentions (v4: CTILE=4, 16 waves, waves_per_eu(4,4))
  PairJob pd  = {hp_hi, hp_lo, hc, F32(31), F32(32), adot};
  PairJob psf = {hc_hi, hc_lo, hc, F32(35), F32(36), aself};
  k_pairattn<<<dim3(40,8,2), dim3(1024), 0, stream>>>(pd, psf);

  // 6) concat & minus attentions (c-tiled)
  AddJob ac_ = {up1, uc2, F32(29),  1.f, acat};
  AddJob am_ = {ump, umc, F32(34), -1.f, amin};
  k_addattn<<<dim3(10,8,2), dim3(256), 0, stream>>>(ac_, am_);

  // 7) bilinear attention
  k_bilattn<<<dim3(160,8), dim3(256), 0, stream>>>(hc, hpWb, abil);

  // 8) ap/rp pooling
  k_tail1<<<dim3(8), dim3(256), 0, stream>>>(upP, F32(38), hp, rp);

  // 9) weighted reps -> agg_in
  k_rep<<<dim3(160,8), dim3(256), 0, stream>>>(hp, hc, acat, abil, adot, amin, aself, aggin);

  // 10) agg xg GEMMs (M=1280, N=384, K=1536)
  GemmSJobs jc = {};
  jc.j[0] = {aggin, w19h, w19l, F32(21), xg_af, 384, 1536, 1536};
  jc.j[1] = {aggin, w23h, w23l, F32(25), xg_ab, 384, 1536, 1536};
  k_gemmS<<<dim3(6,20,2), dim3(256), 0, stream>>>(jc);

  // 11) agg GRU scans (v9)
  GruJobs gja = {};
  gja.j[0] = {xg_af, F32(20), F32(22), agg, 0,   0};
  gja.j[1] = {xg_ab, F32(24), F32(26), agg, 128, 1};
  k_gru<<<dim3(8,2), dim3(512), 0, stream>>>(gja);

  // 12) agg @ W1^T (N=128, K=256)
  GemmSJobs jd = {};
  jd.j[0] = {agg, w39h, w39l, nullptr, aggW1, 128, 256, 256};
  k_gemmS<<<dim3(2,20,1), dim3(256), 0, stream>>>(jd);

  // 13) final scores + output
  k_tail2<<<dim3(8), dim3(256), 0, stream>>>(aggW1, agg, rp, F32(40), F32(41), F32(42), F32(43),
                                             (float*)d_out);
  #undef F32
}

// Round 11
// 819.144 us; speedup vs baseline: 1.0783x; 1.0752x over previous
//
#include <hip/hip_runtime.h>

#define BB 8
#define TT 160
#define EE 300
#define HH 128
#define D2 256
#define G3 384
#define PSTR 40    // padded LDS row stride (shorts) for P tiles
#define HBP 900    // gru hbuf row stride (floats): pads LDS to 83200B -> 1 wg/CU -> VGPR budget 256

typedef __attribute__((ext_vector_type(8))) short bf16x8;
typedef __attribute__((ext_vector_type(4))) float floatx4;

__device__ inline float fsigmoid(float x){ return 1.f/(1.f+__expf(-x)); }
__device__ inline float ftanh(float x){ return 2.f*fsigmoid(2.f*x) - 1.f; }

// truncation split: x ~= hi + lo, each bf16; combined rel err <= ~2^-16
__device__ inline void split2(float x, unsigned short& hi, unsigned short& lo){
  unsigned ux = __float_as_uint(x);
  hi = (unsigned short)(ux>>16);
  float r = x - __uint_as_float(ux & 0xFFFF0000u);
  lo = (unsigned short)(__float_as_uint(r)>>16);
}

// sum across the 4 lanes of a quad (p-dimension) via DPP quad_perm — pure VALU.
__device__ inline float quad_sum(float x){
  x += __uint_as_float(__builtin_amdgcn_mov_dpp(__float_as_uint(x), 0xB1, 0xF, 0xF, true)); // quad_perm [1,0,3,2] : xor 1
  x += __uint_as_float(__builtin_amdgcn_mov_dpp(__float_as_uint(x), 0x4E, 0xF, 0xF, true)); // quad_perm [2,3,0,1] : xor 2
  return x;
}

// ---------------- embedding gather ----------------
__global__ __launch_bounds__(256) void k_embed(const int* ta, const int* tb,
    const float* emb, float* ep, float* ec){
  const int idx = blockIdx.x*256 + threadIdx.x;
  const int per = BB*TT*EE;
  if (idx < per){
    const int e = idx % EE, bt = idx / EE;
    ep[idx] = emb[(long)ta[bt]*EE + e];
  } else {
    const int j = idx - per;
    const int e = j % EE, bt = j / EE;
    ec[j] = emb[(long)tb[bt]*EE + e];
  }
}

// ---------------- hi/lo bf16 split of hp & hc ----------------
__global__ __launch_bounds__(256) void k_splitarr(const float* a, const float* b, int n,
    unsigned short* ahi, unsigned short* alo, unsigned short* bhi, unsigned short* blo){
  const int idx = blockIdx.x*256 + threadIdx.x;
  if (idx < n){
    split2(a[idx], ahi[idx], alo[idx]);
    split2(b[idx], bhi[idx], blo[idx]);
  }
}

// ---------------- weight pre-split: W[N x K](f32) -> hi/lo bf16 [N x Kp], zero-padded ----------------
struct SplitJob { const float* W; unsigned short* hi; unsigned short* lo; int n; int K; int Kp; };
struct SplitJobs { SplitJob j[12]; };

__global__ __launch_bounds__(256) void k_splitw(SplitJobs jobs){
  const SplitJob J = jobs.j[blockIdx.z];
  const int idx = blockIdx.x*256 + threadIdx.x;
  if (idx >= J.n) return;
  const int row = idx / J.Kp, k = idx - row*J.Kp;
  const float v = (k < J.K) ? J.W[(long)row*J.K + k] : 0.f;
  split2(v, J.hi[idx], J.lo[idx]);
}

// ---------------- MFMA GEMM with pre-split W: C = A(f32) @ W^T + bias ----------------
struct GemmSJob {
  const float* A; const unsigned short* Whi; const unsigned short* Wlo; const float* bias;
  float* C; int N; int K; int Kp;
};
struct GemmSJobs { GemmSJob j[6]; };

__global__ __launch_bounds__(256) void k_gemmS(GemmSJobs jobs){
  const GemmSJob J = jobs.j[blockIdx.z];
  const int tid = threadIdx.x;
  const int lane = tid & 63, w = tid >> 6;
  const int l15 = lane & 15, q = lane >> 4;
  const int n0 = blockIdx.x * 64;
  if (n0 >= J.N) return;
  const int K = J.K, Kp = J.Kp;
  const long mrow = blockIdx.y*64 + w*16 + l15;
  const float* Arow = J.A + mrow*K;
  floatx4 acc[4];
  #pragma unroll
  for (int t=0;t<4;t++) acc[t] = (floatx4)0.f;
  const int nch = (K+31)>>5;
  for (int kc=0; kc<nch; kc++){
    const int k0 = kc<<5;
    const int kb = k0 + q*8;
    float av[8];
    if (k0+32 <= K){
      const floatx4 a0 = *(const floatx4*)(Arow+kb);
      const floatx4 a1 = *(const floatx4*)(Arow+kb+4);
      av[0]=a0[0];av[1]=a0[1];av[2]=a0[2];av[3]=a0[3];
      av[4]=a1[0];av[5]=a1[1];av[6]=a1[2];av[7]=a1[3];
    } else {
      #pragma unroll
      for (int j=0;j<8;j++){ const int k=kb+j; av[j] = (k<K)? Arow[k] : 0.f; }
    }
    union { bf16x8 v; unsigned short u[8]; } ahi, alo;
    #pragma unroll
    for (int j=0;j<8;j++) split2(av[j], ahi.u[j], alo.u[j]);
    #pragma unroll
    for (int t=0;t<4;t++){
      const int n = n0 + t*16 + l15;
      const long wo = (long)n*Kp + kb;
      union { bf16x8 v; uint4 d; } whi, wlo;
      whi.d = *(const uint4*)(J.Whi + wo);
      wlo.d = *(const uint4*)(J.Wlo + wo);
      acc[t] = __builtin_amdgcn_mfma_f32_16x16x32_bf16(ahi.v, whi.v, acc[t], 0,0,0);
      acc[t] = __builtin_amdgcn_mfma_f32_16x16x32_bf16(ahi.v, wlo.v, acc[t], 0,0,0);
      acc[t] = __builtin_amdgcn_mfma_f32_16x16x32_bf16(alo.v, whi.v, acc[t], 0,0,0);
    }
  }
  const long rbase = blockIdx.y*64 + w*16 + q*4;
  #pragma unroll
  for (int t=0;t<4;t++){
    const int n = n0 + t*16 + l15;
    const float bv = J.bias ? J.bias[n] : 0.f;
    #pragma unroll
    for (int r=0;r<4;r++)
      J.C[(rbase+r)*(long)J.N + n] = acc[t][r] + bv;
  }
}

// ---------------- GRU scan v10: v8 + LDS-forced VGPR budget ----------------
// Session rule (fits v5-v10 data): VGPR budget = 512 / (waves/SIMD implied by the
// LDS-limited wgs/CU). Attributes (__launch_bounds__ arg2, amdgpu_waves_per_eu)
// did NOT move it; LDS size DOES. v8's 33.8KB -> 4 wgs -> 8 waves/SIMD -> budget 64
// -> the 96-VGPR named-weight set silently spilled (why v8 == v5 perf).
// v10 pads hbuf stride to HBP=900: LDS = 24576+57600+1024 = 83200B > 80KB ->
// exactly 1 wg/CU -> 2 waves/SIMD -> budget 256 -> weights stay in registers.
// Zero occupancy cost: gru has 32 blocks on 256 CUs (<=1 block/CU already).
struct GruJob { const float* xg; const float* Whh; const float* bhh; float* out; int ocol; int rev; };
struct GruJobs { GruJob j[4]; };

__global__ __launch_bounds__(512,1) void k_gru(GruJobs jobs){
  const GruJob J = jobs.j[blockIdx.y];
  const int bi = blockIdx.x;
  const int tid = threadIdx.x;
  const int j = tid >> 2, p = tid & 3;
  const int rot = p*8;
  const int base = p*32;
  __shared__ float xgt[16][G3];
  __shared__ float hbuf[16][HBP];   // row stride 900 floats (3600B, 16B-aligned); only [0..127] used
  __shared__ float hcur[2][HH];
  const float* r0 = J.Whh + (long)j*HH + base;
  const float* z0 = J.Whh + (long)(HH+j)*HH + base;
  const float* n0 = J.Whh + (long)(2*HH+j)*HH + base;
  // 24 named floatx4 = 96 VGPRs of weights; loads use global pointers only.
  #define LDV(gp,i) (*(const floatx4*)((gp) + (((i)*4 + rot) & 31)))
  const floatx4 wr0=LDV(r0,0), wr1=LDV(r0,1), wr2=LDV(r0,2), wr3=LDV(r0,3),
                wr4=LDV(r0,4), wr5=LDV(r0,5), wr6=LDV(r0,6), wr7=LDV(r0,7);
  const floatx4 wz0=LDV(z0,0), wz1=LDV(z0,1), wz2=LDV(z0,2), wz3=LDV(z0,3),
                wz4=LDV(z0,4), wz5=LDV(z0,5), wz6=LDV(z0,6), wz7=LDV(z0,7);
  const floatx4 wn0=LDV(n0,0), wn1=LDV(n0,1), wn2=LDV(n0,2), wn3=LDV(n0,3),
                wn4=LDV(n0,4), wn5=LDV(n0,5), wn6=LDV(n0,6), wn7=LDV(n0,7);
  #undef LDV
  const float bhr = J.bhh[j];
  const float bhz = J.bhh[HH+j];
  const float bhn = J.bhh[2*HH+j];
  if (tid < 256) ((float*)hcur)[tid] = 0.f;
  float hreg = 0.f;
  __syncthreads();

  for (int s0=0; s0<TT; s0+=16){
    #pragma unroll
    for (int r=0;r<3;r++){
      const int i = r*512 + tid;
      const int row = i/96, c4 = i - row*96;
      const int tt = J.rev ? (TT-1-(s0+row)) : (s0+row);
      *(floatx4*)&xgt[row][c4*4] = *(const floatx4*)(J.xg + ((long)bi*TT + tt)*G3 + c4*4);
    }
    __syncthreads();
    for (int si=0; si<16; si++){
      const int s = s0 + si;
      const int buf = s & 1;
      float ar=0.f, az=0.f, an=0.f;
      #define ACC(i) { \
        const floatx4 h4 = *(const floatx4*)&hcur[buf][base + (((i)*4 + rot) & 31)]; \
        ar += wr##i[0]*h4[0] + wr##i[1]*h4[1] + wr##i[2]*h4[2] + wr##i[3]*h4[3]; \
        az += wz##i[0]*h4[0] + wz##i[1]*h4[1] + wz##i[2]*h4[2] + wz##i[3]*h4[3]; \
        an += wn##i[0]*h4[0] + wn##i[1]*h4[1] + wn##i[2]*h4[2] + wn##i[3]*h4[3]; }
      ACC(0) ACC(1) ACC(2) ACC(3) ACC(4) ACC(5) ACC(6) ACC(7)
      #undef ACC
      const float cxr = xgt[si][j];
      const float cxz = xgt[si][HH+j];
      const float cxn = xgt[si][2*HH+j];
      ar = quad_sum(ar);
      az = quad_sum(az);
      an = quad_sum(an);
      const float gr = fsigmoid(cxr + ar + bhr);
      const float gz = fsigmoid(cxz + az + bhz);
      const float gn = ftanh  (cxn + gr*(an + bhn));
      const float h = (1.f-gz)*gn + gz*hreg;
      hreg = h;
      if (p==0){
        hcur[1-buf][j] = h;
        hbuf[si][j] = h;
      }
      __syncthreads();
    }
    {
      const int row = tid >> 5, c4 = tid & 31;
      const int tt = J.rev ? (TT-1-(s0+row)) : (s0+row);
      *(floatx4*)(J.out + ((long)bi*TT + tt)*D2 + J.ocol + c4*4) = *(const floatx4*)&hbuf[row][c4*4];
    }
  }
}

// ---------------- block softmax over 160 values (256 threads) ----------------
__device__ inline float block_softmax160(float s, int tid, float* red){
  float m = s;
  #pragma unroll
  for (int o=32;o>0;o>>=1) m = fmaxf(m, __shfl_xor(m,o));
  if ((tid&63)==0) red[tid>>6] = m;
  __syncthreads();
  m = fmaxf(fmaxf(red[0],red[1]), fmaxf(red[2],red[3]));
  const float p = (tid<TT) ? __expf(s-m) : 0.f;
  float t = p;
  #pragma unroll
  for (int o=32;o>0;o>>=1) t += __shfl_xor(t,o);
  if ((tid&63)==0) red[4+(tid>>6)] = t;
  __syncthreads();
  const float sum = red[4]+red[5]+red[6]+red[7];
  return p / sum;
}

// ---------------- pairwise product attention (dot & self), MFMA + LDS pipeline, CTILE=2 ----------------
// Reverted to the proven R6 v1 (122us, VGPR 84, no spill: LDS 54.8KB -> 2 wgs ->
// 4 waves/SIMD -> budget 128 >= 84). The CTILE=4/1024-thread line (v2-v4) is dead:
// its 58.4KB + 16 waves implied budget 64 -> unavoidable 85MB scratch spill.
struct PairJob { const unsigned short* Phi; const unsigned short* Plo;
                 const float* Q; const float* W; const float* V; float* a_out; };

__global__ __launch_bounds__(512) void k_pairattn(PairJob j0, PairJob j1){
  const PairJob J = blockIdx.z ? j1 : j0;
  const int b = blockIdx.y, c0 = blockIdx.x*2;
  const int tid = threadIdx.x;
  const int lane = tid & 63, w = tid >> 6;
  const int l15 = lane & 15, q = lane >> 4;
  __shared__ unsigned short Pb[2*2*160*PSTR];
  __shared__ float Qs[2][D2];
  __shared__ float sc_sh[2][TT];
  __shared__ float red[16];
  {
    const int row = tid >> 8, col = tid & 255;
    Qs[row][col] = J.Q[((long)b*TT + c0 + row)*D2 + col];
  }
  if (tid < 2*TT) ((float*)sc_sh)[tid] = 0.f;
  const long pbase = (long)b*TT*D2;

  // per-thread staging (5 x uint2 = 20480 B per chunk); pointers hoisted
  const unsigned short* srcp[5];
  unsigned short* dstp[5];
  #pragma unroll
  for (int r=0;r<5;r++){
    const int idx = tid + r*512;
    const int hl = (idx >= 1280) ? 1 : 0;
    const int e4 = idx - hl*1280;
    const int st = e4 >> 3, sd4 = e4 & 7;
    srcp[r] = (hl ? J.Plo : J.Phi) + pbase + (long)st*D2 + sd4*4;
    dstp[r] = &Pb[((0*2 + hl)*160 + st)*PSTR + sd4*4];
  }
  uint2 stg[5];
  #pragma unroll
  for (int r=0;r<5;r++) stg[r] = *(const uint2*)(srcp[r]);
  const float* Wbase = J.W + (long)(w*16 + l15)*D2;
  floatx4 wv0 = *(const floatx4*)(Wbase + q*8);
  floatx4 wv1 = *(const floatx4*)(Wbase + q*8 + 4);
  #pragma unroll
  for (int r=0;r<5;r++) *(uint2*)(dstp[r]) = stg[r];
  __syncthreads();

  floatx4 acc0[10], acc1[10];
  #pragma unroll
  for (int nt=0;nt<10;nt++){ acc0[nt] = (floatx4)0.f; acc1[nt] = (floatx4)0.f; }

  for (int kc=0; kc<8; kc++){
    const floatx4 wc0 = wv0, wc1 = wv1;
    if (kc < 7){
      wv0 = *(const floatx4*)(Wbase + (kc+1)*32 + q*8);
      wv1 = *(const floatx4*)(Wbase + (kc+1)*32 + q*8 + 4);
      #pragma unroll
      for (int r=0;r<5;r++) stg[r] = *(const uint2*)(srcp[r] + (kc+1)*32);
    }
    const int d0 = kc*32 + q*8;
    const floatx4 q00 = *(const floatx4*)&Qs[0][d0];
    const floatx4 q01 = *(const floatx4*)&Qs[0][d0+4];
    const floatx4 q10 = *(const floatx4*)&Qs[1][d0];
    const floatx4 q11 = *(const floatx4*)&Qs[1][d0+4];
    union { bf16x8 v; unsigned short u[8]; } ah0, al0, ah1, al1;
    #pragma unroll
    for (int j=0;j<4;j++){
      split2(wc0[j]*q00[j], ah0.u[j],   al0.u[j]);
      split2(wc1[j]*q01[j], ah0.u[4+j], al0.u[4+j]);
      split2(wc0[j]*q10[j], ah1.u[j],   al1.u[j]);
      split2(wc1[j]*q11[j], ah1.u[4+j], al1.u[4+j]);
    }
    const int buf = kc & 1;
    #pragma unroll
    for (int nt=0;nt<10;nt++){
      const int t = nt*16 + l15;
      union { bf16x8 v; } bh, bl;
      bh.v = *(const bf16x8*)&Pb[((buf*2+0)*160 + t)*PSTR + q*8];
      bl.v = *(const bf16x8*)&Pb[((buf*2+1)*160 + t)*PSTR + q*8];
      acc0[nt] = __builtin_amdgcn_mfma_f32_16x16x32_bf16(ah0.v, bh.v, acc0[nt], 0,0,0);
      acc0[nt] = __builtin_amdgcn_mfma_f32_16x16x32_bf16(ah0.v, bl.v, acc0[nt], 0,0,0);
      acc0[nt] = __builtin_amdgcn_mfma_f32_16x16x32_bf16(al0.v, bh.v, acc0[nt], 0,0,0);
      acc1[nt] = __builtin_amdgcn_mfma_f32_16x16x32_bf16(ah1.v, bh.v, acc1[nt], 0,0,0);
      acc1[nt] = __builtin_amdgcn_mfma_f32_16x16x32_bf16(ah1.v, bl.v, acc1[nt], 0,0,0);
      acc1[nt] = __builtin_amdgcn_mfma_f32_16x16x32_bf16(al1.v, bh.v, acc1[nt], 0,0,0);
    }
    if (kc < 7){
      const int nbuf = 1 - buf;
      #pragma unroll
      for (int r=0;r<5;r++) *(uint2*)(dstp[r] + nbuf*(2*160*PSTR)) = stg[r];
      __syncthreads();
    }
  }

  float vreg[4];
  #pragma unroll
  for (int r=0;r<4;r++) vreg[r] = J.V[w*16 + q*4 + r];
  #pragma unroll
  for (int nt=0;nt<10;nt++){
    float p0 = 0.f, p1 = 0.f;
    #pragma unroll
    for (int r=0;r<4;r++){
      p0 += vreg[r]*ftanh(acc0[nt][r]);
      p1 += vreg[r]*ftanh(acc1[nt][r]);
    }
    p0 += __shfl_xor(p0,16); p0 += __shfl_xor(p0,32);
    p1 += __shfl_xor(p1,16); p1 += __shfl_xor(p1,32);
    if (q==0){
      atomicAdd(&sc_sh[0][nt*16 + l15], p0);
      atomicAdd(&sc_sh[1][nt*16 + l15], p1);
    }
  }
  __syncthreads();
  // two-row softmax: threads 0..255 row 0, 256..511 row 1 (4 waves each)
  {
    const int row = tid >> 8, t_ = tid & 255;
    float s = (t_ < TT) ? sc_sh[row][t_] : -INFINITY;
    float m = s;
    #pragma unroll
    for (int o=32;o>0;o>>=1) m = fmaxf(m, __shfl_xor(m,o));
    if (lane==0) red[w] = m;
    __syncthreads();
    m = fmaxf(fmaxf(red[row*4+0],red[row*4+1]), fmaxf(red[row*4+2],red[row*4+3]));
    const float p = (t_ < TT) ? __expf(s-m) : 0.f;
    float su = p;
    #pragma unroll
    for (int o=32;o>0;o>>=1) su += __shfl_xor(su,o);
    if (lane==0) red[8+w] = su;
    __syncthreads();
    const float ssum = red[8+row*4+0]+red[8+row*4+1]+red[8+row*4+2]+red[8+row*4+3];
    if (t_ < TT) J.a_out[((long)b*TT + c0 + row)*TT + t_] = p/ssum;
  }
}

// ---------------- additive attentions (concat / minus), c-tiled LDS version ----------------
struct AddJob { const float* up; const float* uc; const float* V; float sgn; float* a_out; };

__global__ __launch_bounds__(256) void k_addattn(AddJob j0, AddJob j1){
  const AddJob J = blockIdx.z ? j1 : j0;
  const int b = blockIdx.y, c0 = blockIdx.x*16, tid = threadIdx.x;
  const int ci = tid >> 4, tj = tid & 15;
  __shared__ float ucc[16][132];
  __shared__ float up_sh[16][132];
  __shared__ float vv[HH];
  __shared__ float sc[16][TT];
  if (tid < HH) vv[tid] = J.V[tid];
  for (int i = tid; i < 16*HH; i += 256){
    const int cc = i >> 7, k = i & 127;
    ucc[cc][k] = J.sgn * J.uc[((long)b*TT + c0 + cc)*HH + k];
  }
  __syncthreads();
  for (int tch = 0; tch < 10; tch++){
    for (int i = tid; i < 16*HH; i += 256){
      const int tt = i >> 7, k = i & 127;
      up_sh[tt][k] = J.up[((long)b*TT + tch*16 + tt)*HH + k];
    }
    __syncthreads();
    float a0 = 0.f;
    #pragma unroll 4
    for (int k = 0; k < HH; k += 4){
      const floatx4 u4 = *(const floatx4*)&up_sh[tj][k];
      const floatx4 c4 = *(const floatx4*)&ucc[ci][k];
      a0 += vv[k]*ftanh(u4[0]+c4[0]) + vv[k+1]*ftanh(u4[1]+c4[1])
          + vv[k+2]*ftanh(u4[2]+c4[2]) + vv[k+3]*ftanh(u4[3]+c4[3]);
    }
    sc[ci][tch*16 + tj] = a0;
    __syncthreads();
  }
  float m = -INFINITY;
  float sv[10];
  #pragma unroll
  for (int u = 0; u < 10; u++){ sv[u] = sc[ci][tj + 16*u]; m = fmaxf(m, sv[u]); }
  #pragma unroll
  for (int o = 8; o >= 1; o >>= 1) m = fmaxf(m, __shfl_xor(m, o));
  float ssum = 0.f;
  #pragma unroll
  for (int u = 0; u < 10; u++){ sv[u] = __expf(sv[u] - m); ssum += sv[u]; }
  #pragma unroll
  for (int o = 8; o >= 1; o >>= 1) ssum += __shfl_xor(ssum, o);
  const float inv = 1.f / ssum;
  float* ao = J.a_out + ((long)b*TT + c0 + ci)*TT + tj;
  #pragma unroll
  for (int u = 0; u < 10; u++) ao[16*u] = sv[u]*inv;
}

// ---------------- bilinear attention ----------------
__global__ __launch_bounds__(256) void k_bilattn(const float* hc, const float* hpWb, float* a_out){
  const int b = blockIdx.y, c = blockIdx.x, tid = threadIdx.x;
  __shared__ float hcc[D2];
  __shared__ float red[8];
  if (tid < D2) hcc[tid] = hc[((long)b*TT + c)*D2 + tid];
  __syncthreads();
  float s = -INFINITY;
  if (tid < TT){
    const float* pr = hpWb + ((long)b*TT + tid)*D2;
    float a0 = 0.f;
    #pragma unroll 4
    for (int k=0;k<D2;k++) a0 += hcc[k]*pr[k];
    s = a0;
  }
  const float a = block_softmax160(s, tid, red);
  if (tid < TT) a_out[((long)b*TT + c)*TT + tid] = a;
}

// ---------------- rep build ----------------
__global__ __launch_bounds__(256) void k_rep(const float* hp, const float* hc,
    const float* acat, const float* abil, const float* adot, const float* amin, const float* aself,
    float* aggin){
  const int b = blockIdx.y, c = blockIdx.x, tid = threadIdx.x;
  __shared__ float a5[5][TT];
  {
    const long base = ((long)b*TT + c)*TT;
    for (int i=tid;i<5*TT;i+=256){
      const int which = i/TT, t = i - which*TT;
      const float* p = which==0? acat : which==1? abil : which==2? adot : which==3? amin : aself;
      a5[which][t] = p[base + t];
    }
  }
  __syncthreads();
  const float* hpb = hp + (long)b*TT*D2 + tid;
  const float* hcb = hc + (long)b*TT*D2 + tid;
  float r0=0.f,r1=0.f,r2=0.f,r3=0.f,r4=0.f;
  for (int t=0;t<TT;t++){
    const float vp = hpb[(long)t*D2];
    const float vc = hcb[(long)t*D2];
    r0 += a5[0][t]*vp;
    r1 += a5[1][t]*vp;
    r2 += a5[2][t]*vp;
    r3 += a5[3][t]*vp;
    r4 += a5[4][t]*vc;
  }
  float* o = aggin + ((long)b*TT + c)*(6*D2);
  o[tid]        = hc[((long)b*TT + c)*D2 + tid];
  o[D2 + tid]   = r4;
  o[2*D2 + tid] = r0;
  o[3*D2 + tid] = r2;
  o[4*D2 + tid] = r1;
  o[5*D2 + tid] = r3;
}

// ---------------- tail1 ----------------
__global__ __launch_bounds__(256) void k_tail1(const float* upP, const float* Vp,
    const float* hp, float* rp){
  const int b = blockIdx.x, tid = threadIdx.x;
  __shared__ float vv[HH];
  __shared__ float ap_sh[TT];
  __shared__ float red[8];
  if (tid<HH) vv[tid] = Vp[tid];
  __syncthreads();
  float s = -INFINITY;
  if (tid<TT){
    const float* ur = upP + ((long)b*TT + tid)*HH;
    float a0=0.f;
    #pragma unroll 4
    for (int k=0;k<HH;k++) a0 += vv[k]*ftanh(ur[k]);
    s = a0;
  }
  const float a = block_softmax160(s, tid, red);
  if (tid<TT) ap_sh[tid] = a;
  __syncthreads();
  float acc = 0.f;
  const float* hpb = hp + (long)b*TT*D2 + tid;
  for (int t=0;t<TT;t++) acc += ap_sh[t]*hpb[(long)t*D2];
  rp[b*D2 + tid] = acc;
}

// ---------------- tail2 ----------------
__global__ __launch_bounds__(256) void k_tail2(const float* aggW1, const float* agg, const float* rp,
    const float* W2, const float* Vv, const float* Wout, const float* bout,
    float* out){
  const int b = blockIdx.x, tid = threadIdx.x;
  __shared__ float rps[D2];
  __shared__ float rpw[HH];
  __shared__ float ac_sh[TT];
  __shared__ float rc_sh[D2];
  __shared__ float red[8];
  if (tid < D2) rps[tid] = rp[b*D2 + tid];
  __syncthreads();
  if (tid < HH){
    float a0=0.f;
    const float* wr2 = W2 + (long)tid*D2;
    for (int d=0; d<D2; d+=4){
      const floatx4 w4 = *(const floatx4*)(wr2 + d);
      a0 += w4[0]*rps[d] + w4[1]*rps[d+1] + w4[2]*rps[d+2] + w4[3]*rps[d+3];
    }
    rpw[tid] = a0;
  }
  __syncthreads();
  float s = -INFINITY;
  if (tid < TT){
    const float* ar = aggW1 + ((long)b*TT + tid)*HH;
    float a0=0.f;
    for (int k=0;k<HH;k++) a0 += Vv[k]*(ar[k] + rpw[k]);
    s = a0;
  }
  const float a = block_softmax160(s, tid, red);
  if (tid < TT) ac_sh[tid] = a;
  __syncthreads();
  float rc=0.f;
  const float* ab = agg + (long)b*TT*D2 + tid;
  for (int t=0;t<TT;t++) rc += ac_sh[t]*ab[(long)t*D2];
  rc_sh[tid] = rc;
  __syncthreads();
  if (tid < 2){
    float o = bout[tid];
    const float* wr = Wout + (long)tid*D2;
    for (int d=0; d<D2; d++) o += wr[d]*rc_sh[d];
    out[b*2 + tid] = o;
  }
}

extern "C" void kernel_launch(void* const* d_in, const int* in_sizes, int n_in,
                              void* d_out, int out_size, void* d_ws, size_t ws_size,
                              hipStream_t stream){
  (void)in_sizes; (void)n_in; (void)out_size; (void)ws_size;
  const int* ta = (const int*)d_in[0];
  const int* tb = (const int*)d_in[1];
  const float* emb = (const float*)d_in[2];
  #define F32(i) ((const float*)d_in[i])

  float* ws = (float*)d_ws;
  float* ep    = ws;                 // 8*160*300
  float* ec    = ep    + 384000;
  float* xg_pf = ec    + 384000;     // 8*160*384 each; reused by agg stage later
  float* xg_pb = xg_pf + 491520;
  float* xg_cf = xg_pb + 491520;
  float* xg_cb = xg_cf + 491520;
  float* hp    = xg_cb + 491520;     // 8*160*256
  float* hc    = hp    + 327680;
  float* up1   = hc    + 327680;     // 8*160*128 each
  float* uc2   = up1   + 163840;
  float* ump   = uc2   + 163840;
  float* umc   = ump   + 163840;
  float* upP   = umc   + 163840;
  float* hpWb  = upP   + 163840;     // 8*160*256
  float* acat  = hpWb  + 327680;     // 8*160*160 each
  float* abil  = acat  + 204800;
  float* adot  = abil  + 204800;
  float* amin  = adot  + 204800;
  float* aself = amin  + 204800;
  float* aggin = aself + 204800;     // 8*160*1536
  float* rp    = aggin + 1966080;    // 8*256
  unsigned short* hp_hi = (unsigned short*)(rp + 2048);   // 327680 u16 each
  unsigned short* hp_lo = hp_hi + 327680;
  unsigned short* hc_hi = hp_lo + 327680;
  unsigned short* hc_lo = hc_hi + 327680;
  // pre-split weight region (ushort), padded rows
  unsigned short* wsp = hc_lo + 327680;
  unsigned short* w3h  = wsp;             unsigned short* w3l  = w3h  + 122880;  // 384x320
  unsigned short* w7h  = w3l  + 122880;   unsigned short* w7l  = w7h  + 122880;
  unsigned short* w11h = w7l  + 122880;   unsigned short* w11l = w11h + 122880;
  unsigned short* w15h = w11l + 122880;   unsigned short* w15l = w15h + 122880;
  unsigned short* w27h = w15l + 122880;   unsigned short* w27l = w27h + 32768;   // 128x256
  unsigned short* w28h = w27l + 32768;    unsigned short* w28l = w28h + 32768;
  unsigned short* w33h = w28l + 32768;    unsigned short* w33l = w33h + 32768;
  unsigned short* w37h = w33l + 32768;    unsigned short* w37l = w37h + 32768;
  unsigned short* w30h = w37l + 32768;    unsigned short* w30l = w30h + 65536;   // 256x256
  unsigned short* w19h = w30l + 65536;    unsigned short* w19l = w19h + 589824;  // 384x1536
  unsigned short* w23h = w19l + 589824;   unsigned short* w23l = w23h + 589824;
  unsigned short* w39h = w23l + 589824;   unsigned short* w39l = w39h + 32768;   // 128x256
  // dead-buffer reuse for the agg stage:
  float* xg_af = xg_pf;
  float* xg_ab = xg_pb;
  float* agg   = xg_cf;
  float* aggW1 = xg_cb;

  // 1) embedding gather + weight pre-split
  k_embed<<<dim3(3000), dim3(256), 0, stream>>>(ta, tb, emb, ep, ec);
  SplitJobs sj = {};
  sj.j[0]  = {F32(3),  w3h,  w3l,  122880, 300, 320};
  sj.j[1]  = {F32(7),  w7h,  w7l,  122880, 300, 320};
  sj.j[2]  = {F32(11), w11h, w11l, 122880, 300, 320};
  sj.j[3]  = {F32(15), w15h, w15l, 122880, 300, 320};
  sj.j[4]  = {F32(27), w27h, w27l, 32768,  256, 256};
  sj.j[5]  = {F32(28), w28h, w28l, 32768,  256, 256};
  sj.j[6]  = {F32(33), w33h, w33l, 32768,  256, 256};
  sj.j[7]  = {F32(37), w37h, w37l, 32768,  256, 256};
  sj.j[8]  = {F32(30), w30h, w30l, 65536,  256, 256};
  sj.j[9]  = {F32(19), w19h, w19l, 589824, 1536, 1536};
  sj.j[10] = {F32(23), w23h, w23l, 589824, 1536, 1536};
  sj.j[11] = {F32(39), w39h, w39l, 32768,  256, 256};
  k_splitw<<<dim3(2304,1,12), dim3(256), 0, stream>>>(sj);

  // 2) xg = x @ Wih^T + bih for p/c  (M=1280, N=384, K=300, Kp=320)
  GemmSJobs ja = {};
  ja.j[0] = {ep, w3h,  w3l,  F32(5),  xg_pf, 384, 300, 320};
  ja.j[1] = {ep, w7h,  w7l,  F32(9),  xg_pb, 384, 300, 320};
  ja.j[2] = {ec, w11h, w11l, F32(13), xg_cf, 384, 300, 320};
  ja.j[3] = {ec, w15h, w15l, F32(17), xg_cb, 384, 300, 320};
  k_gemmS<<<dim3(6,20,4), dim3(256), 0, stream>>>(ja);

  // 3) p/c GRU scans (v10: LDS-forced register budget)
  GruJobs gj = {};
  gj.j[0] = {xg_pf, F32(4),  F32(6),  hp, 0,   0};
  gj.j[1] = {xg_pb, F32(8),  F32(10), hp, 128, 1};
  gj.j[2] = {xg_cf, F32(12), F32(14), hc, 0,   0};
  gj.j[3] = {xg_cb, F32(16), F32(18), hc, 128, 1};
  k_gru<<<dim3(8,4), dim3(512), 0, stream>>>(gj);

  // 3b) hi/lo split of hp & hc for pairattn B-operands
  k_splitarr<<<dim3(1280), dim3(256), 0, stream>>>(hp, hc, 327680, hp_hi, hp_lo, hc_hi, hc_lo);

  // 4) projection GEMMs (K=256)
  GemmSJobs jb = {};
  jb.j[0] = {hp, w27h, w27l, nullptr, up1,  128, 256, 256};
  jb.j[1] = {hc, w28h, w28l, nullptr, uc2,  128, 256, 256};
  jb.j[2] = {hp, w33h, w33l, nullptr, ump,  128, 256, 256};
  jb.j[3] = {hc, w33h, w33l, nullptr, umc,  128, 256, 256};
  jb.j[4] = {hp, w37h, w37l, nullptr, upP,  128, 256, 256};
  jb.j[5] = {hp, w30h, w30l, nullptr, hpWb, 256, 256, 256};
  k_gemmS<<<dim3(4,20,6), dim3(256), 0, stream>>>(jb);

  // 5) dot & self attentions (v1: CTILE=2, 512 threads — proven no-spill)
  PairJob pd  = {hp_hi, hp_lo, hc, F32(31), F32(32), adot};
  PairJob psf = {hc_hi, hc_lo, hc, F32(35), F32(36), aself};
  k_pairattn<<<dim3(80,8,2), dim3(512), 0, stream>>>(pd, psf);

  // 6) concat & minus attentions (c-tiled)
  AddJob ac_ = {up1, uc2, F32(29),  1.f, acat};
  AddJob am_ = {ump, umc, F32(34), -1.f, amin};
  k_addattn<<<dim3(10,8,2), dim3(256), 0, stream>>>(ac_, am_);

  // 7) bilinear attention
  k_bilattn<<<dim3(160,8), dim3(256), 0, stream>>>(hc, hpWb, abil);

  // 8) ap/rp pooling
  k_tail1<<<dim3(8), dim3(256), 0, stream>>>(upP, F32(38), hp, rp);

  // 9) weighted reps -> agg_in
  k_rep<<<dim3(160,8), dim3(256), 0, stream>>>(hp, hc, acat, abil, adot, amin, aself, aggin);

  // 10) agg xg GEMMs (M=1280, N=384, K=1536)
  GemmSJobs jc = {};
  jc.j[0] = {aggin, w19h, w19l, F32(21), xg_af, 384, 1536, 1536};
  jc.j[1] = {aggin, w23h, w23l, F32(25), xg_ab, 384, 1536, 1536};
  k_gemmS<<<dim3(6,20,2), dim3(256), 0, stream>>>(jc);

  // 11) agg GRU scans (v10)
  GruJobs gja = {};
  gja.j[0] = {xg_af, F32(20), F32(22), agg, 0,   0};
  gja.j[1] = {xg_ab, F32(24), F32(26), agg, 128, 1};
  k_gru<<<dim3(8,2), dim3(512), 0, stream>>>(gja);

  // 12) agg @ W1^T (N=128, K=256)
  GemmSJobs jd = {};
  jd.j[0] = {agg, w39h, w39l, nullptr, aggW1, 128, 256, 256};
  k_gemmS<<<dim3(2,20,1), dim3(256), 0, stream>>>(jd);

  // 13) final scores + output
  k_tail2<<<dim3(8), dim3(256), 0, stream>>>(aggW1, agg, rp, F32(40), F32(41), F32(42), F32(43),
                                             (float*)d_out);
  #undef F32
}